// Round 1
// baseline (545.826 us; speedup 1.0000x reference)
//
#include <hip/hip_runtime.h>
#include <hip/hip_bf16.h>

#define N_NODES 50000
#define HEADS 4
#define DHEAD 32
#define F 128           // HEADS*DHEAD = in/out feature width everywhere
#define NEG_SLOPE 0.2f

// ---------------------------------------------------------------------------
// CSR build: histogram -> scan -> scatter
// ---------------------------------------------------------------------------
__global__ void hist_kernel(const int* __restrict__ dst, int* __restrict__ counts, int E) {
    int i = blockIdx.x * 256 + threadIdx.x;
    if (i < E) atomicAdd(&counts[dst[i]], 1);
}

// single block, 1024 threads; counts -> exclusive offsets (and cursor copy)
__global__ void scan_kernel(int* __restrict__ counts, int* __restrict__ offsets,
                            int* __restrict__ cursor, int N) {
    __shared__ int part[1024];
    int tid = threadIdx.x;
    int chunk = (N + 1023) / 1024;
    int lo = tid * chunk;
    int hi = lo + chunk; if (hi > N) hi = N; if (lo > N) lo = N;
    int sum = 0;
    for (int i = lo; i < hi; i++) sum += counts[i];
    part[tid] = sum;
    __syncthreads();
    for (int off = 1; off < 1024; off <<= 1) {
        int v = (tid >= off) ? part[tid - off] : 0;
        __syncthreads();
        part[tid] += v;
        __syncthreads();
    }
    int prefix = (tid == 0) ? 0 : part[tid - 1];
    for (int i = lo; i < hi; i++) {
        int c = counts[i];
        offsets[i] = prefix;
        cursor[i] = prefix;
        prefix += c;
    }
    if (tid == 1023) offsets[N] = part[1023];
}

__global__ void scatter_kernel(const int* __restrict__ src, const int* __restrict__ dst,
                               int* __restrict__ cursor, int* __restrict__ csr_src, int E) {
    int i = blockIdx.x * 256 + threadIdx.x;
    if (i < E) {
        int p = atomicAdd(&cursor[dst[i]], 1);
        csr_src[p] = src[i];
    }
}

// ---------------------------------------------------------------------------
// fp32 GEMM: C[M,128] = A[M,128] @ B[128,128] (+bias). Tile 64 rows x 64 cols.
// ---------------------------------------------------------------------------
template <bool BIAS>
__global__ __launch_bounds__(256) void gemm_kernel(const float* __restrict__ A,
                                                   const float* __restrict__ B,
                                                   const float* __restrict__ bias,
                                                   float* __restrict__ C, int M) {
    __shared__ float sB[128 * 64];      // [k][64 cols]
    __shared__ float sAT[128 * 66];     // [k][64 rows + pad2]
    int tid = threadIdx.x;
    int row0 = blockIdx.x * 64;
    int col0 = blockIdx.y * 64;

    // stage B tile (128 x 64)
    for (int i = tid; i < 128 * 16; i += 256) {
        int r = i >> 4, c4 = i & 15;
        float4 v = *(const float4*)(B + r * 128 + col0 + 4 * c4);
        *(float4*)(&sB[r * 64 + 4 * c4]) = v;
    }
    // stage A tile transposed (64 rows x 128 k -> sAT[k][row])
    for (int i = tid; i < 64 * 32; i += 256) {
        int r = i >> 5, c4 = i & 31;
        int gr = row0 + r;
        float4 v = make_float4(0.f, 0.f, 0.f, 0.f);
        if (gr < M) v = *(const float4*)(A + (size_t)gr * 128 + 4 * c4);
        sAT[(4 * c4 + 0) * 66 + r] = v.x;
        sAT[(4 * c4 + 1) * 66 + r] = v.y;
        sAT[(4 * c4 + 2) * 66 + r] = v.z;
        sAT[(4 * c4 + 3) * 66 + r] = v.w;
    }
    __syncthreads();

    int tx = tid & 15;        // 16 col-groups of 4 cols
    int ty = tid >> 4;        // 16 row-groups of 4 rows
    const float* pB = sB + 4 * tx;
    const float* pA = sAT + 4 * ty;
    float acc[4][4] = {};
#pragma unroll 4
    for (int k = 0; k < 128; k++) {
        float4 b = *(const float4*)(pB + k * 64);
        float2 a01 = *(const float2*)(pA + k * 66);
        float2 a23 = *(const float2*)(pA + k * 66 + 2);
        float a[4] = {a01.x, a01.y, a23.x, a23.y};
        float bb[4] = {b.x, b.y, b.z, b.w};
#pragma unroll
        for (int j = 0; j < 4; j++)
#pragma unroll
            for (int c = 0; c < 4; c++) acc[j][c] = fmaf(a[j], bb[c], acc[j][c]);
    }

    float4 bv = make_float4(0.f, 0.f, 0.f, 0.f);
    if (BIAS) bv = *(const float4*)(bias + col0 + 4 * tx);
#pragma unroll
    for (int j = 0; j < 4; j++) {
        int gr = row0 + ty * 4 + j;
        if (gr < M) {
            float4 v;
            v.x = acc[j][0] + bv.x;
            v.y = acc[j][1] + bv.y;
            v.z = acc[j][2] + bv.z;
            v.w = acc[j][3] + bv.w;
            *(float4*)(C + (size_t)gr * 128 + col0 + 4 * tx) = v;
        }
    }
}

// ---------------------------------------------------------------------------
// el/er: per (node,head) dot of feat[n,h,:] with al[h,:], ar[h,:]
// ---------------------------------------------------------------------------
__global__ void eler_kernel(const float* __restrict__ feat, const float* __restrict__ al,
                            const float* __restrict__ ar, float* __restrict__ el,
                            float* __restrict__ er, int NH) {
    int idx = blockIdx.x * 256 + threadIdx.x;
    if (idx >= NH) return;
    int h = idx & 3;
    const float* f = feat + (size_t)idx * 32;
    const float* a_l = al + h * 32;
    const float* a_r = ar + h * 32;
    float sl = 0.f, sr = 0.f;
#pragma unroll
    for (int i = 0; i < 32; i += 4) {
        float4 fv = *(const float4*)(f + i);
        float4 lv = *(const float4*)(a_l + i);
        float4 rv = *(const float4*)(a_r + i);
        sl += fv.x * lv.x + fv.y * lv.y + fv.z * lv.z + fv.w * lv.w;
        sr += fv.x * rv.x + fv.y * rv.y + fv.z * rv.z + fv.w * rv.w;
    }
    el[idx] = sl;
    er[idx] = sr;
}

// ---------------------------------------------------------------------------
// Aggregate: one wave per node. Pass1 online-softmax (lanes parallel over
// edges, shuffle-merged), pass2 serial edge loop, each lane owns 2 columns.
// ---------------------------------------------------------------------------
__global__ __launch_bounds__(256) void aggregate_kernel(
    const float* __restrict__ feat, const float* __restrict__ el,
    const float* __restrict__ er, const float* __restrict__ bias,
    const int* __restrict__ offsets, const int* __restrict__ csr_src,
    float* __restrict__ out, int N) {
    int lane = threadIdx.x & 63;
    int n = blockIdx.x * 4 + (threadIdx.x >> 6);
    if (n >= N) return;
    int start = offsets[n], end = offsets[n + 1];

    float er_h[4];
#pragma unroll
    for (int h = 0; h < 4; h++) er_h[h] = er[n * 4 + h];

    float m[4], s[4];
#pragma unroll
    for (int h = 0; h < 4; h++) { m[h] = -1e30f; s[h] = 0.f; }

    for (int e = start + lane; e < end; e += 64) {
        int sv = csr_src[e];
        const float* ep = el + (size_t)sv * 4;
#pragma unroll
        for (int h = 0; h < 4; h++) {
            float v = ep[h] + er_h[h];
            v = (v >= 0.f) ? v : NEG_SLOPE * v;
            float mn = fmaxf(m[h], v);
            s[h] = s[h] * __expf(m[h] - mn) + __expf(v - mn);
            m[h] = mn;
        }
    }
#pragma unroll
    for (int off = 32; off; off >>= 1) {
#pragma unroll
        for (int h = 0; h < 4; h++) {
            float mo = __shfl_xor(m[h], off);
            float so = __shfl_xor(s[h], off);
            float mn = fmaxf(m[h], mo);
            s[h] = s[h] * __expf(m[h] - mn) + so * __expf(mo - mn);
            m[h] = mn;
        }
    }

    int c0 = lane * 2;
    int h0 = lane >> 4;   // both owned columns are in the same head
    float mh = m[h0];
    float rz = (end > start) ? 1.0f / s[h0] : 0.f;
    float erh = er_h[h0];
    float acc0 = 0.f, acc1 = 0.f;
    for (int e = start; e < end; e++) {
        int sv = csr_src[e];
        float v = el[(size_t)sv * 4 + h0] + erh;
        v = (v >= 0.f) ? v : NEG_SLOPE * v;
        float alpha = __expf(v - mh) * rz;
        float2 f2 = *(const float2*)(feat + (size_t)sv * 128 + c0);
        acc0 = fmaf(alpha, f2.x, acc0);
        acc1 = fmaf(alpha, f2.y, acc1);
    }
    float2 o;
    o.x = acc0 + bias[c0];
    o.y = acc1 + bias[c0 + 1];
    *(float2*)(out + (size_t)n * 128 + c0) = o;
}

// ---------------------------------------------------------------------------
extern "C" void kernel_launch(void* const* d_in, const int* in_sizes, int n_in,
                              void* d_out, int out_size, void* d_ws, size_t ws_size,
                              hipStream_t stream) {
    const float* x   = (const float*)d_in[0];
    const int*   src = (const int*)d_in[1];
    const int*   dst = (const int*)d_in[2];
    const float* W1  = (const float*)d_in[3];
    const float* al1 = (const float*)d_in[4];
    const float* ar1 = (const float*)d_in[5];
    const float* b1  = (const float*)d_in[6];
    const float* W2  = (const float*)d_in[7];
    const float* al2 = (const float*)d_in[8];
    const float* ar2 = (const float*)d_in[9];
    const float* b2  = (const float*)d_in[10];
    const float* Wp  = (const float*)d_in[11];
    const float* bp  = (const float*)d_in[12];

    const int N = in_sizes[0] / F;      // 50000
    const int E = in_sizes[1];          // 800000

    float* h_out = (float*)d_out;               // [N,128]  (layer-2 output h)
    float* p_out = h_out + (size_t)N * F;       // [N,128]  (projection output)

    // workspace carve
    char* w = (char*)d_ws;
    float* feat   = (float*)w;                                  // N*128 f32
    float* el     = (float*)(w + (size_t)N * F * 4);            // N*4
    float* er     = el + (size_t)N * 4;                         // N*4
    int*   offs   = (int*)(er + (size_t)N * 4);                 // N+1
    int*   cursor = offs + (N + 1);                             // N
    int*   csrsrc = cursor + N;                                 // E

    float* h1 = p_out;  // use d_out second half as layer-1 output scratch

    // --- CSR build (dst is identical for both layers) ---
    hipMemsetAsync(cursor, 0, (size_t)N * 4, stream);
    hist_kernel<<<(E + 255) / 256, 256, 0, stream>>>(dst, cursor, E);
    scan_kernel<<<1, 1024, 0, stream>>>(cursor, offs, cursor, N);
    scatter_kernel<<<(E + 255) / 256, 256, 0, stream>>>(src, dst, cursor, csrsrc, E);

    dim3 ggrid((N + 63) / 64, 2);

    // --- layer 1 ---
    gemm_kernel<false><<<ggrid, 256, 0, stream>>>(x, W1, nullptr, feat, N);
    eler_kernel<<<(N * 4 + 255) / 256, 256, 0, stream>>>(feat, al1, ar1, el, er, N * 4);
    aggregate_kernel<<<(N + 3) / 4, 256, 0, stream>>>(feat, el, er, b1, offs, csrsrc, h1, N);

    // --- layer 2 ---
    gemm_kernel<false><<<ggrid, 256, 0, stream>>>(h1, W2, nullptr, feat, N);
    eler_kernel<<<(N * 4 + 255) / 256, 256, 0, stream>>>(feat, al2, ar2, el, er, N * 4);
    aggregate_kernel<<<(N + 3) / 4, 256, 0, stream>>>(feat, el, er, b2, offs, csrsrc, h_out, N);

    // --- projection (reads h_out, overwrites h1 region with final output) ---
    gemm_kernel<true><<<ggrid, 256, 0, stream>>>(h_out, Wp, bp, p_out, N);
}

// Round 2
// 381.387 us; speedup vs baseline: 1.4312x; 1.4312x over previous
//
#include <hip/hip_runtime.h>
#include <hip/hip_bf16.h>

#define N_NODES 50000
#define HEADS 4
#define DHEAD 32
#define F 128           // HEADS*DHEAD = in/out feature width everywhere
#define NEG_SLOPE 0.2f

// ---------------------------------------------------------------------------
// CSR build: histogram -> hierarchical scan -> scatter
// ---------------------------------------------------------------------------
__global__ void hist_kernel(const int* __restrict__ dst, int* __restrict__ counts, int E) {
    int i = blockIdx.x * 256 + threadIdx.x;
    if (i < E) atomicAdd(&counts[dst[i]], 1);
}

// Block-level exclusive scan of counts -> local_sc; per-block total -> partials
__global__ __launch_bounds__(256) void scanA_kernel(const int* __restrict__ counts,
                                                    int* __restrict__ local_sc,
                                                    int* __restrict__ partials, int N) {
    int i = blockIdx.x * 256 + threadIdx.x;
    int v = (i < N) ? counts[i] : 0;
    int lane = threadIdx.x & 63;
    int w = threadIdx.x >> 6;
    int x = v;
#pragma unroll
    for (int off = 1; off < 64; off <<= 1) {
        int t = __shfl_up(x, off);
        if (lane >= off) x += t;
    }
    __shared__ int wsum[4];
    if (lane == 63) wsum[w] = x;
    __syncthreads();
    int wpre = 0;
#pragma unroll
    for (int k = 0; k < 4; k++)
        if (k < w) wpre += wsum[k];
    if (i < N) local_sc[i] = x - v + wpre;            // exclusive within block
    if (threadIdx.x == 255) partials[blockIdx.x] = wpre + x;  // block total
}

// Single block: exclusive scan of partials in place (NP <= 256)
__global__ void scanB_kernel(int* __restrict__ partials, int NP) {
    int tid = threadIdx.x;
    int v = (tid < NP) ? partials[tid] : 0;
    int lane = tid & 63;
    int w = tid >> 6;
    int x = v;
#pragma unroll
    for (int off = 1; off < 64; off <<= 1) {
        int t = __shfl_up(x, off);
        if (lane >= off) x += t;
    }
    __shared__ int wsum[4];
    if (lane == 63) wsum[w] = x;
    __syncthreads();
    int wpre = 0;
#pragma unroll
    for (int k = 0; k < 4; k++)
        if (k < w) wpre += wsum[k];
    if (tid < NP) partials[tid] = x - v + wpre;
}

// Add block offsets; produce final offsets + cursor copy
__global__ __launch_bounds__(256) void scanC_kernel(int* __restrict__ offs,
                                                    int* __restrict__ cursor,
                                                    const int* __restrict__ partials,
                                                    int N, int E) {
    int i = blockIdx.x * 256 + threadIdx.x;
    if (i < N) {
        int o = offs[i] + partials[blockIdx.x];
        offs[i] = o;
        cursor[i] = o;
    }
    if (i == 0) offs[N] = E;
}

__global__ void scatter_kernel(const int* __restrict__ src, const int* __restrict__ dst,
                               int* __restrict__ cursor, int* __restrict__ csr_src, int E) {
    int i = blockIdx.x * 256 + threadIdx.x;
    if (i < E) {
        int p = atomicAdd(&cursor[dst[i]], 1);
        csr_src[p] = src[i];
    }
}

// ---------------------------------------------------------------------------
// fp32 GEMM: C[M,128] = A[M,128] @ B[128,128] (+bias). Tile 64 rows x 64 cols.
// ---------------------------------------------------------------------------
template <bool BIAS>
__global__ __launch_bounds__(256) void gemm_kernel(const float* __restrict__ A,
                                                   const float* __restrict__ B,
                                                   const float* __restrict__ bias,
                                                   float* __restrict__ C, int M) {
    __shared__ float sB[128 * 64];      // [k][64 cols]
    __shared__ float sAT[128 * 66];     // [k][64 rows + pad2]
    int tid = threadIdx.x;
    int row0 = blockIdx.x * 64;
    int col0 = blockIdx.y * 64;

    for (int i = tid; i < 128 * 16; i += 256) {
        int r = i >> 4, c4 = i & 15;
        float4 v = *(const float4*)(B + r * 128 + col0 + 4 * c4);
        *(float4*)(&sB[r * 64 + 4 * c4]) = v;
    }
    for (int i = tid; i < 64 * 32; i += 256) {
        int r = i >> 5, c4 = i & 31;
        int gr = row0 + r;
        float4 v = make_float4(0.f, 0.f, 0.f, 0.f);
        if (gr < M) v = *(const float4*)(A + (size_t)gr * 128 + 4 * c4);
        sAT[(4 * c4 + 0) * 66 + r] = v.x;
        sAT[(4 * c4 + 1) * 66 + r] = v.y;
        sAT[(4 * c4 + 2) * 66 + r] = v.z;
        sAT[(4 * c4 + 3) * 66 + r] = v.w;
    }
    __syncthreads();

    int tx = tid & 15;
    int ty = tid >> 4;
    const float* pB = sB + 4 * tx;
    const float* pA = sAT + 4 * ty;
    float acc[4][4] = {};
#pragma unroll 4
    for (int k = 0; k < 128; k++) {
        float4 b = *(const float4*)(pB + k * 64);
        float2 a01 = *(const float2*)(pA + k * 66);
        float2 a23 = *(const float2*)(pA + k * 66 + 2);
        float a[4] = {a01.x, a01.y, a23.x, a23.y};
        float bb[4] = {b.x, b.y, b.z, b.w};
#pragma unroll
        for (int j = 0; j < 4; j++)
#pragma unroll
            for (int c = 0; c < 4; c++) acc[j][c] = fmaf(a[j], bb[c], acc[j][c]);
    }

    float4 bv = make_float4(0.f, 0.f, 0.f, 0.f);
    if (BIAS) bv = *(const float4*)(bias + col0 + 4 * tx);
#pragma unroll
    for (int j = 0; j < 4; j++) {
        int gr = row0 + ty * 4 + j;
        if (gr < M) {
            float4 v;
            v.x = acc[j][0] + bv.x;
            v.y = acc[j][1] + bv.y;
            v.z = acc[j][2] + bv.z;
            v.w = acc[j][3] + bv.w;
            *(float4*)(C + (size_t)gr * 128 + col0 + 4 * tx) = v;
        }
    }
}

// ---------------------------------------------------------------------------
// el/er: per (node,head) dot of feat[n,h,:] with al[h,:], ar[h,:]
// ---------------------------------------------------------------------------
__global__ void eler_kernel(const float* __restrict__ feat, const float* __restrict__ al,
                            const float* __restrict__ ar, float* __restrict__ el,
                            float* __restrict__ er, int NH) {
    int idx = blockIdx.x * 256 + threadIdx.x;
    if (idx >= NH) return;
    int h = idx & 3;
    const float* f = feat + (size_t)idx * 32;
    const float* a_l = al + h * 32;
    const float* a_r = ar + h * 32;
    float sl = 0.f, sr = 0.f;
#pragma unroll
    for (int i = 0; i < 32; i += 4) {
        float4 fv = *(const float4*)(f + i);
        float4 lv = *(const float4*)(a_l + i);
        float4 rv = *(const float4*)(a_r + i);
        sl += fv.x * lv.x + fv.y * lv.y + fv.z * lv.z + fv.w * lv.w;
        sr += fv.x * rv.x + fv.y * rv.y + fv.z * rv.z + fv.w * rv.w;
    }
    el[idx] = sl;
    er[idx] = sr;
}

// ---------------------------------------------------------------------------
// Aggregate: 16 lanes per node (4 nodes per wave). Pass1 online-softmax with
// full lane utilization (deg ~16), 4-step xor reduce within the 16-lane group.
// Pass2: serial edge loop, each lane owns 8 columns (2x float4 loads).
// ---------------------------------------------------------------------------
__global__ __launch_bounds__(256) void aggregate_kernel(
    const float* __restrict__ feat, const float* __restrict__ el,
    const float* __restrict__ er, const float* __restrict__ bias,
    const int* __restrict__ offsets, const int* __restrict__ csr_src,
    float* __restrict__ out, int N) {
    int tid = threadIdx.x;
    int gl = tid & 15;                      // lane within 16-lane group
    int n = blockIdx.x * 16 + (tid >> 4);   // node
    if (n >= N) return;
    int start = offsets[n], end = offsets[n + 1];

    float4 erv = *(const float4*)(er + (size_t)n * 4);
    float er_h[4] = {erv.x, erv.y, erv.z, erv.w};

    float m[4], s[4];
#pragma unroll
    for (int h = 0; h < 4; h++) { m[h] = -1e30f; s[h] = 0.f; }

    for (int e = start + gl; e < end; e += 16) {
        int sv = csr_src[e];
        float4 ev = *(const float4*)(el + (size_t)sv * 4);
        float elh[4] = {ev.x, ev.y, ev.z, ev.w};
#pragma unroll
        for (int h = 0; h < 4; h++) {
            float v = elh[h] + er_h[h];
            v = (v >= 0.f) ? v : NEG_SLOPE * v;
            float mn = fmaxf(m[h], v);
            s[h] = s[h] * __expf(m[h] - mn) + __expf(v - mn);
            m[h] = mn;
        }
    }
#pragma unroll
    for (int off = 1; off < 16; off <<= 1) {
#pragma unroll
        for (int h = 0; h < 4; h++) {
            float mo = __shfl_xor(m[h], off);
            float so = __shfl_xor(s[h], off);
            float mn = fmaxf(m[h], mo);
            s[h] = s[h] * __expf(m[h] - mn) + so * __expf(mo - mn);
            m[h] = mn;
        }
    }

    int h0 = gl >> 2;                       // head for my 8 columns
    int c0 = gl * 8;
    float mh  = (h0 < 2) ? (h0 == 0 ? m[0] : m[1]) : (h0 == 2 ? m[2] : m[3]);
    float sh  = (h0 < 2) ? (h0 == 0 ? s[0] : s[1]) : (h0 == 2 ? s[2] : s[3]);
    float erh = (h0 < 2) ? (h0 == 0 ? er_h[0] : er_h[1]) : (h0 == 2 ? er_h[2] : er_h[3]);
    float rz = (end > start) ? 1.0f / sh : 0.f;

    float acc[8] = {};
    int e = start;
    for (; e + 1 < end; e += 2) {
        int sv0 = csr_src[e];
        int sv1 = csr_src[e + 1];
        float v0 = el[(size_t)sv0 * 4 + h0] + erh;
        float v1 = el[(size_t)sv1 * 4 + h0] + erh;
        v0 = (v0 >= 0.f) ? v0 : NEG_SLOPE * v0;
        v1 = (v1 >= 0.f) ? v1 : NEG_SLOPE * v1;
        float a0 = __expf(v0 - mh) * rz;
        float a1 = __expf(v1 - mh) * rz;
        float4 f00 = *(const float4*)(feat + (size_t)sv0 * 128 + c0);
        float4 f01 = *(const float4*)(feat + (size_t)sv0 * 128 + c0 + 4);
        float4 f10 = *(const float4*)(feat + (size_t)sv1 * 128 + c0);
        float4 f11 = *(const float4*)(feat + (size_t)sv1 * 128 + c0 + 4);
        acc[0] = fmaf(a0, f00.x, acc[0]); acc[1] = fmaf(a0, f00.y, acc[1]);
        acc[2] = fmaf(a0, f00.z, acc[2]); acc[3] = fmaf(a0, f00.w, acc[3]);
        acc[4] = fmaf(a0, f01.x, acc[4]); acc[5] = fmaf(a0, f01.y, acc[5]);
        acc[6] = fmaf(a0, f01.z, acc[6]); acc[7] = fmaf(a0, f01.w, acc[7]);
        acc[0] = fmaf(a1, f10.x, acc[0]); acc[1] = fmaf(a1, f10.y, acc[1]);
        acc[2] = fmaf(a1, f10.z, acc[2]); acc[3] = fmaf(a1, f10.w, acc[3]);
        acc[4] = fmaf(a1, f11.x, acc[4]); acc[5] = fmaf(a1, f11.y, acc[5]);
        acc[6] = fmaf(a1, f11.z, acc[6]); acc[7] = fmaf(a1, f11.w, acc[7]);
    }
    if (e < end) {
        int sv = csr_src[e];
        float v = el[(size_t)sv * 4 + h0] + erh;
        v = (v >= 0.f) ? v : NEG_SLOPE * v;
        float a0 = __expf(v - mh) * rz;
        float4 f0 = *(const float4*)(feat + (size_t)sv * 128 + c0);
        float4 f1 = *(const float4*)(feat + (size_t)sv * 128 + c0 + 4);
        acc[0] = fmaf(a0, f0.x, acc[0]); acc[1] = fmaf(a0, f0.y, acc[1]);
        acc[2] = fmaf(a0, f0.z, acc[2]); acc[3] = fmaf(a0, f0.w, acc[3]);
        acc[4] = fmaf(a0, f1.x, acc[4]); acc[5] = fmaf(a0, f1.y, acc[5]);
        acc[6] = fmaf(a0, f1.z, acc[6]); acc[7] = fmaf(a0, f1.w, acc[7]);
    }

    float4 b0 = *(const float4*)(bias + c0);
    float4 b1 = *(const float4*)(bias + c0 + 4);
    float4 o0, o1;
    o0.x = acc[0] + b0.x; o0.y = acc[1] + b0.y; o0.z = acc[2] + b0.z; o0.w = acc[3] + b0.w;
    o1.x = acc[4] + b1.x; o1.y = acc[5] + b1.y; o1.z = acc[6] + b1.z; o1.w = acc[7] + b1.w;
    *(float4*)(out + (size_t)n * 128 + c0) = o0;
    *(float4*)(out + (size_t)n * 128 + c0 + 4) = o1;
}

// ---------------------------------------------------------------------------
extern "C" void kernel_launch(void* const* d_in, const int* in_sizes, int n_in,
                              void* d_out, int out_size, void* d_ws, size_t ws_size,
                              hipStream_t stream) {
    const float* x   = (const float*)d_in[0];
    const int*   src = (const int*)d_in[1];
    const int*   dst = (const int*)d_in[2];
    const float* W1  = (const float*)d_in[3];
    const float* al1 = (const float*)d_in[4];
    const float* ar1 = (const float*)d_in[5];
    const float* b1  = (const float*)d_in[6];
    const float* W2  = (const float*)d_in[7];
    const float* al2 = (const float*)d_in[8];
    const float* ar2 = (const float*)d_in[9];
    const float* b2  = (const float*)d_in[10];
    const float* Wp  = (const float*)d_in[11];
    const float* bp  = (const float*)d_in[12];

    const int N = in_sizes[0] / F;      // 50000
    const int E = in_sizes[1];          // 800000

    float* h_out = (float*)d_out;               // [N,128]  (layer-2 output h)
    float* p_out = h_out + (size_t)N * F;       // [N,128]  (projection output)

    // workspace carve
    char* w = (char*)d_ws;
    float* feat     = (float*)w;                                // N*128 f32
    float* el       = (float*)(w + (size_t)N * F * 4);          // N*4
    float* er       = el + (size_t)N * 4;                       // N*4
    int*   offs     = (int*)(er + (size_t)N * 4);               // N+1
    int*   cursor   = offs + (N + 1);                           // N
    int*   csrsrc   = cursor + N;                               // E
    int*   partials = csrsrc + E;                               // 256

    float* h1 = p_out;  // use d_out second half as layer-1 output scratch

    const int NB = (N + 255) / 256;     // scan blocks (196)

    // --- CSR build (dst is identical for both layers) ---
    hipMemsetAsync(cursor, 0, (size_t)N * 4, stream);
    hist_kernel<<<(E + 255) / 256, 256, 0, stream>>>(dst, cursor, E);
    scanA_kernel<<<NB, 256, 0, stream>>>(cursor, offs, partials, N);
    scanB_kernel<<<1, 256, 0, stream>>>(partials, NB);
    scanC_kernel<<<NB, 256, 0, stream>>>(offs, cursor, partials, N, E);
    scatter_kernel<<<(E + 255) / 256, 256, 0, stream>>>(src, dst, cursor, csrsrc, E);

    dim3 ggrid((N + 63) / 64, 2);
    int agrid = (N + 15) / 16;

    // --- layer 1 ---
    gemm_kernel<false><<<ggrid, 256, 0, stream>>>(x, W1, nullptr, feat, N);
    eler_kernel<<<(N * 4 + 255) / 256, 256, 0, stream>>>(feat, al1, ar1, el, er, N * 4);
    aggregate_kernel<<<agrid, 256, 0, stream>>>(feat, el, er, b1, offs, csrsrc, h1, N);

    // --- layer 2 ---
    gemm_kernel<false><<<ggrid, 256, 0, stream>>>(h1, W2, nullptr, feat, N);
    eler_kernel<<<(N * 4 + 255) / 256, 256, 0, stream>>>(feat, al2, ar2, el, er, N * 4);
    aggregate_kernel<<<agrid, 256, 0, stream>>>(feat, el, er, b2, offs, csrsrc, h_out, N);

    // --- projection (reads h_out, overwrites h1 region with final output) ---
    gemm_kernel<true><<<ggrid, 256, 0, stream>>>(h_out, Wp, bp, p_out, N);
}

// Round 3
// 319.431 us; speedup vs baseline: 1.7087x; 1.1940x over previous
//
#include <hip/hip_runtime.h>
#include <hip/hip_bf16.h>

#define N_NODES 50000
#define HEADS 4
#define DHEAD 32
#define F 128           // HEADS*DHEAD = in/out feature width everywhere
#define NEG_SLOPE 0.2f

typedef unsigned int uint;
typedef unsigned short ushort;

__device__ __forceinline__ float bf2f(ushort u) {
    union { uint i; float f; } c; c.i = ((uint)u) << 16; return c.f;
}
__device__ __forceinline__ ushort f2bf(float f) {
    union { float f; uint i; } c; c.f = f;
    uint u = c.i + 0x7FFF + ((c.i >> 16) & 1);   // round-to-nearest-even
    return (ushort)(u >> 16);
}

// ---------------------------------------------------------------------------
// CSR build: histogram -> hierarchical scan -> scatter
// ---------------------------------------------------------------------------
__global__ void hist_kernel(const int* __restrict__ dst, int* __restrict__ counts, int E) {
    int i = blockIdx.x * 256 + threadIdx.x;
    if (i < E) atomicAdd(&counts[dst[i]], 1);
}

__global__ __launch_bounds__(256) void scanA_kernel(const int* __restrict__ counts,
                                                    int* __restrict__ local_sc,
                                                    int* __restrict__ partials, int N) {
    int i = blockIdx.x * 256 + threadIdx.x;
    int v = (i < N) ? counts[i] : 0;
    int lane = threadIdx.x & 63;
    int w = threadIdx.x >> 6;
    int x = v;
#pragma unroll
    for (int off = 1; off < 64; off <<= 1) {
        int t = __shfl_up(x, off);
        if (lane >= off) x += t;
    }
    __shared__ int wsum[4];
    if (lane == 63) wsum[w] = x;
    __syncthreads();
    int wpre = 0;
#pragma unroll
    for (int k = 0; k < 4; k++)
        if (k < w) wpre += wsum[k];
    if (i < N) local_sc[i] = x - v + wpre;
    if (threadIdx.x == 255) partials[blockIdx.x] = wpre + x;
}

__global__ void scanB_kernel(int* __restrict__ partials, int NP) {
    int tid = threadIdx.x;
    int v = (tid < NP) ? partials[tid] : 0;
    int lane = tid & 63;
    int w = tid >> 6;
    int x = v;
#pragma unroll
    for (int off = 1; off < 64; off <<= 1) {
        int t = __shfl_up(x, off);
        if (lane >= off) x += t;
    }
    __shared__ int wsum[4];
    if (lane == 63) wsum[w] = x;
    __syncthreads();
    int wpre = 0;
#pragma unroll
    for (int k = 0; k < 4; k++)
        if (k < w) wpre += wsum[k];
    if (tid < NP) partials[tid] = x - v + wpre;
}

__global__ __launch_bounds__(256) void scanC_kernel(int* __restrict__ offs,
                                                    int* __restrict__ cursor,
                                                    const int* __restrict__ partials,
                                                    int N, int E) {
    int i = blockIdx.x * 256 + threadIdx.x;
    if (i < N) {
        int o = offs[i] + partials[blockIdx.x];
        offs[i] = o;
        cursor[i] = o;
    }
    if (i == 0) offs[N] = E;
}

__global__ void scatter_kernel(const int* __restrict__ src, const int* __restrict__ dst,
                               int* __restrict__ cursor, int* __restrict__ csr_src, int E) {
    int i = blockIdx.x * 256 + threadIdx.x;
    if (i < E) {
        int p = atomicAdd(&cursor[dst[i]], 1);
        csr_src[p] = src[i];
    }
}

// ---------------------------------------------------------------------------
// fp32 GEMM: C[M,128] = A[M,128] @ B[128,128] (+bias). Tile 64 rows x 64 cols.
// OUT_BF16: write bf16 (packed) instead of fp32.
// ---------------------------------------------------------------------------
template <bool BIAS, bool OUT_BF16>
__global__ __launch_bounds__(256) void gemm_kernel(const float* __restrict__ A,
                                                   const float* __restrict__ B,
                                                   const float* __restrict__ bias,
                                                   void* __restrict__ Cv, int M) {
    __shared__ float sB[128 * 64];      // [k][64 cols]
    __shared__ float sAT[128 * 66];     // [k][64 rows + pad2]
    int tid = threadIdx.x;
    int row0 = blockIdx.x * 64;
    int col0 = blockIdx.y * 64;

    for (int i = tid; i < 128 * 16; i += 256) {
        int r = i >> 4, c4 = i & 15;
        float4 v = *(const float4*)(B + r * 128 + col0 + 4 * c4);
        *(float4*)(&sB[r * 64 + 4 * c4]) = v;
    }
    for (int i = tid; i < 64 * 32; i += 256) {
        int r = i >> 5, c4 = i & 31;
        int gr = row0 + r;
        float4 v = make_float4(0.f, 0.f, 0.f, 0.f);
        if (gr < M) v = *(const float4*)(A + (size_t)gr * 128 + 4 * c4);
        sAT[(4 * c4 + 0) * 66 + r] = v.x;
        sAT[(4 * c4 + 1) * 66 + r] = v.y;
        sAT[(4 * c4 + 2) * 66 + r] = v.z;
        sAT[(4 * c4 + 3) * 66 + r] = v.w;
    }
    __syncthreads();

    int tx = tid & 15;
    int ty = tid >> 4;
    const float* pB = sB + 4 * tx;
    const float* pA = sAT + 4 * ty;
    float acc[4][4] = {};
#pragma unroll 4
    for (int k = 0; k < 128; k++) {
        float4 b = *(const float4*)(pB + k * 64);
        float2 a01 = *(const float2*)(pA + k * 66);
        float2 a23 = *(const float2*)(pA + k * 66 + 2);
        float a[4] = {a01.x, a01.y, a23.x, a23.y};
        float bb[4] = {b.x, b.y, b.z, b.w};
#pragma unroll
        for (int j = 0; j < 4; j++)
#pragma unroll
            for (int c = 0; c < 4; c++) acc[j][c] = fmaf(a[j], bb[c], acc[j][c]);
    }

    float4 bv = make_float4(0.f, 0.f, 0.f, 0.f);
    if (BIAS) bv = *(const float4*)(bias + col0 + 4 * tx);
#pragma unroll
    for (int j = 0; j < 4; j++) {
        int gr = row0 + ty * 4 + j;
        if (gr < M) {
            float v0 = acc[j][0] + bv.x;
            float v1 = acc[j][1] + bv.y;
            float v2 = acc[j][2] + bv.z;
            float v3 = acc[j][3] + bv.w;
            if (OUT_BF16) {
                uint2 p;
                p.x = (uint)f2bf(v0) | ((uint)f2bf(v1) << 16);
                p.y = (uint)f2bf(v2) | ((uint)f2bf(v3) << 16);
                ushort* C = (ushort*)Cv;
                *(uint2*)(C + (size_t)gr * 128 + col0 + 4 * tx) = p;
            } else {
                float4 v; v.x = v0; v.y = v1; v.z = v2; v.w = v3;
                float* C = (float*)Cv;
                *(float4*)(C + (size_t)gr * 128 + col0 + 4 * tx) = v;
            }
        }
    }
}

// ---------------------------------------------------------------------------
// el/er from bf16 feat: per (node,head) dot with al[h,:], ar[h,:]
// ---------------------------------------------------------------------------
__global__ void eler_kernel(const ushort* __restrict__ featb, const float* __restrict__ al,
                            const float* __restrict__ ar, float* __restrict__ el,
                            float* __restrict__ er, int NH) {
    int idx = blockIdx.x * 256 + threadIdx.x;
    if (idx >= NH) return;
    int h = idx & 3;
    const ushort* f = featb + (size_t)idx * 32;
    const float* a_l = al + h * 32;
    const float* a_r = ar + h * 32;
    float sl = 0.f, sr = 0.f;
#pragma unroll
    for (int q = 0; q < 4; q++) {
        uint4 fv = *(const uint4*)(f + q * 8);
        float fx[8] = {bf2f(fv.x & 0xFFFF), bf2f(fv.x >> 16),
                       bf2f(fv.y & 0xFFFF), bf2f(fv.y >> 16),
                       bf2f(fv.z & 0xFFFF), bf2f(fv.z >> 16),
                       bf2f(fv.w & 0xFFFF), bf2f(fv.w >> 16)};
        float4 lv0 = *(const float4*)(a_l + q * 8);
        float4 lv1 = *(const float4*)(a_l + q * 8 + 4);
        float4 rv0 = *(const float4*)(a_r + q * 8);
        float4 rv1 = *(const float4*)(a_r + q * 8 + 4);
        sl += fx[0] * lv0.x + fx[1] * lv0.y + fx[2] * lv0.z + fx[3] * lv0.w
            + fx[4] * lv1.x + fx[5] * lv1.y + fx[6] * lv1.z + fx[7] * lv1.w;
        sr += fx[0] * rv0.x + fx[1] * rv0.y + fx[2] * rv0.z + fx[3] * rv0.w
            + fx[4] * rv1.x + fx[5] * rv1.y + fx[6] * rv1.z + fx[7] * rv1.w;
    }
    el[idx] = sl;
    er[idx] = sr;
}

// ---------------------------------------------------------------------------
// Aggregate: 16 lanes per node (4 nodes per wave). Pass1 online-softmax over
// edges (lane-parallel), 4-step xor reduce. Pass2 serial edge loop, each lane
// owns 8 columns = one 16B bf16 load per edge.
// ---------------------------------------------------------------------------
__global__ __launch_bounds__(256) void aggregate_kernel(
    const ushort* __restrict__ featb, const float* __restrict__ el,
    const float* __restrict__ er, const float* __restrict__ bias,
    const int* __restrict__ offsets, const int* __restrict__ csr_src,
    float* __restrict__ out, int N) {
    int tid = threadIdx.x;
    int gl = tid & 15;
    int n = blockIdx.x * 16 + (tid >> 4);
    if (n >= N) return;
    int start = offsets[n], end = offsets[n + 1];

    float4 erv = *(const float4*)(er + (size_t)n * 4);
    float er_h[4] = {erv.x, erv.y, erv.z, erv.w};

    float m[4], s[4];
#pragma unroll
    for (int h = 0; h < 4; h++) { m[h] = -1e30f; s[h] = 0.f; }

    for (int e = start + gl; e < end; e += 16) {
        int sv = csr_src[e];
        float4 ev = *(const float4*)(el + (size_t)sv * 4);
        float elh[4] = {ev.x, ev.y, ev.z, ev.w};
#pragma unroll
        for (int h = 0; h < 4; h++) {
            float v = elh[h] + er_h[h];
            v = (v >= 0.f) ? v : NEG_SLOPE * v;
            float mn = fmaxf(m[h], v);
            s[h] = s[h] * __expf(m[h] - mn) + __expf(v - mn);
            m[h] = mn;
        }
    }
#pragma unroll
    for (int off = 1; off < 16; off <<= 1) {
#pragma unroll
        for (int h = 0; h < 4; h++) {
            float mo = __shfl_xor(m[h], off);
            float so = __shfl_xor(s[h], off);
            float mn = fmaxf(m[h], mo);
            s[h] = s[h] * __expf(m[h] - mn) + so * __expf(mo - mn);
            m[h] = mn;
        }
    }

    int h0 = gl >> 2;
    int c0 = gl * 8;
    float mh  = (h0 < 2) ? (h0 == 0 ? m[0] : m[1]) : (h0 == 2 ? m[2] : m[3]);
    float sh  = (h0 < 2) ? (h0 == 0 ? s[0] : s[1]) : (h0 == 2 ? s[2] : s[3]);
    float erh = (h0 < 2) ? (h0 == 0 ? er_h[0] : er_h[1]) : (h0 == 2 ? er_h[2] : er_h[3]);
    float rz = (end > start) ? 1.0f / sh : 0.f;

    float acc[8] = {};
    int e = start;
    for (; e + 1 < end; e += 2) {
        int sv0 = csr_src[e];
        int sv1 = csr_src[e + 1];
        float v0 = el[(size_t)sv0 * 4 + h0] + erh;
        float v1 = el[(size_t)sv1 * 4 + h0] + erh;
        v0 = (v0 >= 0.f) ? v0 : NEG_SLOPE * v0;
        v1 = (v1 >= 0.f) ? v1 : NEG_SLOPE * v1;
        float a0 = __expf(v0 - mh) * rz;
        float a1 = __expf(v1 - mh) * rz;
        uint4 f0 = *(const uint4*)(featb + (size_t)sv0 * 128 + c0);
        uint4 f1 = *(const uint4*)(featb + (size_t)sv1 * 128 + c0);
        acc[0] = fmaf(a0, bf2f(f0.x & 0xFFFF), acc[0]);
        acc[1] = fmaf(a0, bf2f(f0.x >> 16),    acc[1]);
        acc[2] = fmaf(a0, bf2f(f0.y & 0xFFFF), acc[2]);
        acc[3] = fmaf(a0, bf2f(f0.y >> 16),    acc[3]);
        acc[4] = fmaf(a0, bf2f(f0.z & 0xFFFF), acc[4]);
        acc[5] = fmaf(a0, bf2f(f0.z >> 16),    acc[5]);
        acc[6] = fmaf(a0, bf2f(f0.w & 0xFFFF), acc[6]);
        acc[7] = fmaf(a0, bf2f(f0.w >> 16),    acc[7]);
        acc[0] = fmaf(a1, bf2f(f1.x & 0xFFFF), acc[0]);
        acc[1] = fmaf(a1, bf2f(f1.x >> 16),    acc[1]);
        acc[2] = fmaf(a1, bf2f(f1.y & 0xFFFF), acc[2]);
        acc[3] = fmaf(a1, bf2f(f1.y >> 16),    acc[3]);
        acc[4] = fmaf(a1, bf2f(f1.z & 0xFFFF), acc[4]);
        acc[5] = fmaf(a1, bf2f(f1.z >> 16),    acc[5]);
        acc[6] = fmaf(a1, bf2f(f1.w & 0xFFFF), acc[6]);
        acc[7] = fmaf(a1, bf2f(f1.w >> 16),    acc[7]);
    }
    if (e < end) {
        int sv = csr_src[e];
        float v = el[(size_t)sv * 4 + h0] + erh;
        v = (v >= 0.f) ? v : NEG_SLOPE * v;
        float a0 = __expf(v - mh) * rz;
        uint4 f0 = *(const uint4*)(featb + (size_t)sv * 128 + c0);
        acc[0] = fmaf(a0, bf2f(f0.x & 0xFFFF), acc[0]);
        acc[1] = fmaf(a0, bf2f(f0.x >> 16),    acc[1]);
        acc[2] = fmaf(a0, bf2f(f0.y & 0xFFFF), acc[2]);
        acc[3] = fmaf(a0, bf2f(f0.y >> 16),    acc[3]);
        acc[4] = fmaf(a0, bf2f(f0.z & 0xFFFF), acc[4]);
        acc[5] = fmaf(a0, bf2f(f0.z >> 16),    acc[5]);
        acc[6] = fmaf(a0, bf2f(f0.w & 0xFFFF), acc[6]);
        acc[7] = fmaf(a0, bf2f(f0.w >> 16),    acc[7]);
    }

    float4 b0 = *(const float4*)(bias + c0);
    float4 b1 = *(const float4*)(bias + c0 + 4);
    float4 o0, o1;
    o0.x = acc[0] + b0.x; o0.y = acc[1] + b0.y; o0.z = acc[2] + b0.z; o0.w = acc[3] + b0.w;
    o1.x = acc[4] + b1.x; o1.y = acc[5] + b1.y; o1.z = acc[6] + b1.z; o1.w = acc[7] + b1.w;
    *(float4*)(out + (size_t)n * 128 + c0) = o0;
    *(float4*)(out + (size_t)n * 128 + c0 + 4) = o1;
}

// ---------------------------------------------------------------------------
extern "C" void kernel_launch(void* const* d_in, const int* in_sizes, int n_in,
                              void* d_out, int out_size, void* d_ws, size_t ws_size,
                              hipStream_t stream) {
    const float* x   = (const float*)d_in[0];
    const int*   src = (const int*)d_in[1];
    const int*   dst = (const int*)d_in[2];
    const float* W1  = (const float*)d_in[3];
    const float* al1 = (const float*)d_in[4];
    const float* ar1 = (const float*)d_in[5];
    const float* b1  = (const float*)d_in[6];
    const float* W2  = (const float*)d_in[7];
    const float* al2 = (const float*)d_in[8];
    const float* ar2 = (const float*)d_in[9];
    const float* b2  = (const float*)d_in[10];
    const float* Wp  = (const float*)d_in[11];
    const float* bp  = (const float*)d_in[12];

    const int N = in_sizes[0] / F;      // 50000
    const int E = in_sizes[1];          // 800000

    float* h_out = (float*)d_out;               // [N,128]  (layer-2 output h)
    float* p_out = h_out + (size_t)N * F;       // [N,128]  (projection output)

    // workspace carve
    char* w = (char*)d_ws;
    ushort* featb   = (ushort*)w;                               // N*128 bf16
    float* el       = (float*)(w + (size_t)N * F * 2);          // N*4
    float* er       = el + (size_t)N * 4;                       // N*4
    int*   offs     = (int*)(er + (size_t)N * 4);               // N+1
    int*   cursor   = offs + (N + 1);                           // N
    int*   csrsrc   = cursor + N;                               // E
    int*   partials = csrsrc + E;                               // 256

    float* h1 = p_out;  // use d_out second half as layer-1 output scratch

    const int NB = (N + 255) / 256;

    // --- CSR build (dst is identical for both layers) ---
    hipMemsetAsync(cursor, 0, (size_t)N * 4, stream);
    hist_kernel<<<(E + 255) / 256, 256, 0, stream>>>(dst, cursor, E);
    scanA_kernel<<<NB, 256, 0, stream>>>(cursor, offs, partials, N);
    scanB_kernel<<<1, 256, 0, stream>>>(partials, NB);
    scanC_kernel<<<NB, 256, 0, stream>>>(offs, cursor, partials, N, E);
    scatter_kernel<<<(E + 255) / 256, 256, 0, stream>>>(src, dst, cursor, csrsrc, E);

    dim3 ggrid((N + 63) / 64, 2);
    int agrid = (N + 15) / 16;

    // --- layer 1 ---
    gemm_kernel<false, true><<<ggrid, 256, 0, stream>>>(x, W1, nullptr, featb, N);
    eler_kernel<<<(N * 4 + 255) / 256, 256, 0, stream>>>(featb, al1, ar1, el, er, N * 4);
    aggregate_kernel<<<agrid, 256, 0, stream>>>(featb, el, er, b1, offs, csrsrc, h1, N);

    // --- layer 2 ---
    gemm_kernel<false, true><<<ggrid, 256, 0, stream>>>(h1, W2, nullptr, featb, N);
    eler_kernel<<<(N * 4 + 255) / 256, 256, 0, stream>>>(featb, al2, ar2, el, er, N * 4);
    aggregate_kernel<<<agrid, 256, 0, stream>>>(featb, el, er, b2, offs, csrsrc, h_out, N);

    // --- projection (reads h_out fp32, writes fp32 + bias) ---
    gemm_kernel<true, false><<<ggrid, 256, 0, stream>>>(h_out, Wp, bp, p_out, N);
}

// Round 4
// 292.001 us; speedup vs baseline: 1.8693x; 1.0939x over previous
//
#include <hip/hip_runtime.h>
#include <hip/hip_bf16.h>

#define N_NODES 50000
#define HEADS 4
#define DHEAD 32
#define F 128           // HEADS*DHEAD = in/out feature width everywhere
#define NEG_SLOPE 0.2f

typedef unsigned int uint;
typedef unsigned short ushort;

__device__ __forceinline__ float bf2f(ushort u) {
    union { uint i; float f; } c; c.i = ((uint)u) << 16; return c.f;
}
__device__ __forceinline__ ushort f2bf(float f) {
    union { float f; uint i; } c; c.f = f;
    uint u = c.i + 0x7FFF + ((c.i >> 16) & 1);   // round-to-nearest-even
    return (ushort)(u >> 16);
}

// ---------------------------------------------------------------------------
// CSR build: rank+hist -> hierarchical scan -> posfix -> range-split scatter
// ---------------------------------------------------------------------------
// counts[dst]++ returning old value = this edge's rank within its dst segment
__global__ void rank_hist_kernel(const int* __restrict__ dst, int* __restrict__ counts,
                                 int* __restrict__ rank, int E) {
    int i = blockIdx.x * 256 + threadIdx.x;
    if (i < E) rank[i] = atomicAdd(&counts[dst[i]], 1);
}

__global__ __launch_bounds__(256) void scanA_kernel(const int* __restrict__ counts,
                                                    int* __restrict__ local_sc,
                                                    int* __restrict__ partials, int N) {
    int i = blockIdx.x * 256 + threadIdx.x;
    int v = (i < N) ? counts[i] : 0;
    int lane = threadIdx.x & 63;
    int w = threadIdx.x >> 6;
    int x = v;
#pragma unroll
    for (int off = 1; off < 64; off <<= 1) {
        int t = __shfl_up(x, off);
        if (lane >= off) x += t;
    }
    __shared__ int wsum[4];
    if (lane == 63) wsum[w] = x;
    __syncthreads();
    int wpre = 0;
#pragma unroll
    for (int k = 0; k < 4; k++)
        if (k < w) wpre += wsum[k];
    if (i < N) local_sc[i] = x - v + wpre;
    if (threadIdx.x == 255) partials[blockIdx.x] = wpre + x;
}

__global__ void scanB_kernel(int* __restrict__ partials, int NP) {
    int tid = threadIdx.x;
    int v = (tid < NP) ? partials[tid] : 0;
    int lane = tid & 63;
    int w = tid >> 6;
    int x = v;
#pragma unroll
    for (int off = 1; off < 64; off <<= 1) {
        int t = __shfl_up(x, off);
        if (lane >= off) x += t;
    }
    __shared__ int wsum[4];
    if (lane == 63) wsum[w] = x;
    __syncthreads();
    int wpre = 0;
#pragma unroll
    for (int k = 0; k < 4; k++)
        if (k < w) wpre += wsum[k];
    if (tid < NP) partials[tid] = x - v + wpre;
}

__global__ __launch_bounds__(256) void scanC_kernel(int* __restrict__ offs,
                                                    const int* __restrict__ partials,
                                                    int N, int E) {
    int i = blockIdx.x * 256 + threadIdx.x;
    if (i < N) offs[i] += partials[blockIdx.x];
    if (i == 0) offs[N] = E;
}

// rank[i] -> final CSR position p = offs[dst[i]] + rank[i]  (in place)
__global__ void posfix_kernel(const int* __restrict__ dst, const int* __restrict__ offs,
                              int* __restrict__ rank, int E) {
    int i = blockIdx.x * 256 + threadIdx.x;
    if (i < E) rank[i] += offs[dst[i]];
}

// Range-split scatter: blockIdx&7 selects one of 8 contiguous position
// windows (maps to one XCD under round-robin dispatch), so each 64B line of
// csr_src is produced by a single XCD's L2 and written back once, full.
#define SCH 2048   // edges per block chunk
__global__ __launch_bounds__(256) void scatter_ranged_kernel(
    const int* __restrict__ src, const int* __restrict__ pos,
    int* __restrict__ csr_src, int E) {
    int range = blockIdx.x & 7;
    int chunk = blockIdx.x >> 3;
    int base = chunk * SCH + threadIdx.x;
    int lo = (int)(((long long)range * E) >> 3);
    int hi = (int)(((long long)(range + 1) * E) >> 3);
#pragma unroll
    for (int k = 0; k < SCH / 256; k++) {
        int i = base + k * 256;
        if (i < E) {
            int p = pos[i];
            if (p >= lo && p < hi) csr_src[p] = src[i];
        }
    }
}

// ---------------------------------------------------------------------------
// fp32 GEMM: C[M,128] = A[M,128] @ B[128,128] (+bias). Tile 64 rows x 64 cols.
// OUT_BF16: write bf16 (packed) instead of fp32.
// ---------------------------------------------------------------------------
template <bool BIAS, bool OUT_BF16>
__global__ __launch_bounds__(256) void gemm_kernel(const float* __restrict__ A,
                                                   const float* __restrict__ B,
                                                   const float* __restrict__ bias,
                                                   void* __restrict__ Cv, int M) {
    __shared__ float sB[128 * 64];      // [k][64 cols]
    __shared__ float sAT[128 * 66];     // [k][64 rows + pad2]
    int tid = threadIdx.x;
    int row0 = blockIdx.x * 64;
    int col0 = blockIdx.y * 64;

    for (int i = tid; i < 128 * 16; i += 256) {
        int r = i >> 4, c4 = i & 15;
        float4 v = *(const float4*)(B + r * 128 + col0 + 4 * c4);
        *(float4*)(&sB[r * 64 + 4 * c4]) = v;
    }
    for (int i = tid; i < 64 * 32; i += 256) {
        int r = i >> 5, c4 = i & 31;
        int gr = row0 + r;
        float4 v = make_float4(0.f, 0.f, 0.f, 0.f);
        if (gr < M) v = *(const float4*)(A + (size_t)gr * 128 + 4 * c4);
        sAT[(4 * c4 + 0) * 66 + r] = v.x;
        sAT[(4 * c4 + 1) * 66 + r] = v.y;
        sAT[(4 * c4 + 2) * 66 + r] = v.z;
        sAT[(4 * c4 + 3) * 66 + r] = v.w;
    }
    __syncthreads();

    int tx = tid & 15;
    int ty = tid >> 4;
    const float* pB = sB + 4 * tx;
    const float* pA = sAT + 4 * ty;
    float acc[4][4] = {};
#pragma unroll 4
    for (int k = 0; k < 128; k++) {
        float4 b = *(const float4*)(pB + k * 64);
        float2 a01 = *(const float2*)(pA + k * 66);
        float2 a23 = *(const float2*)(pA + k * 66 + 2);
        float a[4] = {a01.x, a01.y, a23.x, a23.y};
        float bb[4] = {b.x, b.y, b.z, b.w};
#pragma unroll
        for (int j = 0; j < 4; j++)
#pragma unroll
            for (int c = 0; c < 4; c++) acc[j][c] = fmaf(a[j], bb[c], acc[j][c]);
    }

    float4 bv = make_float4(0.f, 0.f, 0.f, 0.f);
    if (BIAS) bv = *(const float4*)(bias + col0 + 4 * tx);
#pragma unroll
    for (int j = 0; j < 4; j++) {
        int gr = row0 + ty * 4 + j;
        if (gr < M) {
            float v0 = acc[j][0] + bv.x;
            float v1 = acc[j][1] + bv.y;
            float v2 = acc[j][2] + bv.z;
            float v3 = acc[j][3] + bv.w;
            if (OUT_BF16) {
                uint2 p;
                p.x = (uint)f2bf(v0) | ((uint)f2bf(v1) << 16);
                p.y = (uint)f2bf(v2) | ((uint)f2bf(v3) << 16);
                ushort* C = (ushort*)Cv;
                *(uint2*)(C + (size_t)gr * 128 + col0 + 4 * tx) = p;
            } else {
                float4 v; v.x = v0; v.y = v1; v.z = v2; v.w = v3;
                float* C = (float*)Cv;
                *(float4*)(C + (size_t)gr * 128 + col0 + 4 * tx) = v;
            }
        }
    }
}

// ---------------------------------------------------------------------------
// el/er from bf16 feat: per (node,head) dot with al[h,:], ar[h,:]
// ---------------------------------------------------------------------------
__global__ void eler_kernel(const ushort* __restrict__ featb, const float* __restrict__ al,
                            const float* __restrict__ ar, float* __restrict__ el,
                            float* __restrict__ er, int NH) {
    int idx = blockIdx.x * 256 + threadIdx.x;
    if (idx >= NH) return;
    int h = idx & 3;
    const ushort* f = featb + (size_t)idx * 32;
    const float* a_l = al + h * 32;
    const float* a_r = ar + h * 32;
    float sl = 0.f, sr = 0.f;
#pragma unroll
    for (int q = 0; q < 4; q++) {
        uint4 fv = *(const uint4*)(f + q * 8);
        float fx[8] = {bf2f(fv.x & 0xFFFF), bf2f(fv.x >> 16),
                       bf2f(fv.y & 0xFFFF), bf2f(fv.y >> 16),
                       bf2f(fv.z & 0xFFFF), bf2f(fv.z >> 16),
                       bf2f(fv.w & 0xFFFF), bf2f(fv.w >> 16)};
        float4 lv0 = *(const float4*)(a_l + q * 8);
        float4 lv1 = *(const float4*)(a_l + q * 8 + 4);
        float4 rv0 = *(const float4*)(a_r + q * 8);
        float4 rv1 = *(const float4*)(a_r + q * 8 + 4);
        sl += fx[0] * lv0.x + fx[1] * lv0.y + fx[2] * lv0.z + fx[3] * lv0.w
            + fx[4] * lv1.x + fx[5] * lv1.y + fx[6] * lv1.z + fx[7] * lv1.w;
        sr += fx[0] * rv0.x + fx[1] * rv0.y + fx[2] * rv0.z + fx[3] * rv0.w
            + fx[4] * rv1.x + fx[5] * rv1.y + fx[6] * rv1.z + fx[7] * rv1.w;
    }
    el[idx] = sl;
    er[idx] = sr;
}

// ---------------------------------------------------------------------------
// Aggregate: 16 lanes per node (4 nodes per wave). Pass1 online-softmax over
// edges (lane-parallel), 4-step xor reduce. Pass2 serial edge loop, each lane
// owns 8 columns = one 16B bf16 load per edge.
// ---------------------------------------------------------------------------
__global__ __launch_bounds__(256) void aggregate_kernel(
    const ushort* __restrict__ featb, const float* __restrict__ el,
    const float* __restrict__ er, const float* __restrict__ bias,
    const int* __restrict__ offsets, const int* __restrict__ csr_src,
    float* __restrict__ out, int N) {
    int tid = threadIdx.x;
    int gl = tid & 15;
    int n = blockIdx.x * 16 + (tid >> 4);
    if (n >= N) return;
    int start = offsets[n], end = offsets[n + 1];

    float4 erv = *(const float4*)(er + (size_t)n * 4);
    float er_h[4] = {erv.x, erv.y, erv.z, erv.w};

    float m[4], s[4];
#pragma unroll
    for (int h = 0; h < 4; h++) { m[h] = -1e30f; s[h] = 0.f; }

    for (int e = start + gl; e < end; e += 16) {
        int sv = csr_src[e];
        float4 ev = *(const float4*)(el + (size_t)sv * 4);
        float elh[4] = {ev.x, ev.y, ev.z, ev.w};
#pragma unroll
        for (int h = 0; h < 4; h++) {
            float v = elh[h] + er_h[h];
            v = (v >= 0.f) ? v : NEG_SLOPE * v;
            float mn = fmaxf(m[h], v);
            s[h] = s[h] * __expf(m[h] - mn) + __expf(v - mn);
            m[h] = mn;
        }
    }
#pragma unroll
    for (int off = 1; off < 16; off <<= 1) {
#pragma unroll
        for (int h = 0; h < 4; h++) {
            float mo = __shfl_xor(m[h], off);
            float so = __shfl_xor(s[h], off);
            float mn = fmaxf(m[h], mo);
            s[h] = s[h] * __expf(m[h] - mn) + so * __expf(mo - mn);
            m[h] = mn;
        }
    }

    int h0 = gl >> 2;
    int c0 = gl * 8;
    float mh  = (h0 < 2) ? (h0 == 0 ? m[0] : m[1]) : (h0 == 2 ? m[2] : m[3]);
    float sh  = (h0 < 2) ? (h0 == 0 ? s[0] : s[1]) : (h0 == 2 ? s[2] : s[3]);
    float erh = (h0 < 2) ? (h0 == 0 ? er_h[0] : er_h[1]) : (h0 == 2 ? er_h[2] : er_h[3]);
    float rz = (end > start) ? 1.0f / sh : 0.f;

    float acc[8] = {};
    int e = start;
    for (; e + 1 < end; e += 2) {
        int sv0 = csr_src[e];
        int sv1 = csr_src[e + 1];
        float v0 = el[(size_t)sv0 * 4 + h0] + erh;
        float v1 = el[(size_t)sv1 * 4 + h0] + erh;
        v0 = (v0 >= 0.f) ? v0 : NEG_SLOPE * v0;
        v1 = (v1 >= 0.f) ? v1 : NEG_SLOPE * v1;
        float a0 = __expf(v0 - mh) * rz;
        float a1 = __expf(v1 - mh) * rz;
        uint4 f0 = *(const uint4*)(featb + (size_t)sv0 * 128 + c0);
        uint4 f1 = *(const uint4*)(featb + (size_t)sv1 * 128 + c0);
        acc[0] = fmaf(a0, bf2f(f0.x & 0xFFFF), acc[0]);
        acc[1] = fmaf(a0, bf2f(f0.x >> 16),    acc[1]);
        acc[2] = fmaf(a0, bf2f(f0.y & 0xFFFF), acc[2]);
        acc[3] = fmaf(a0, bf2f(f0.y >> 16),    acc[3]);
        acc[4] = fmaf(a0, bf2f(f0.z & 0xFFFF), acc[4]);
        acc[5] = fmaf(a0, bf2f(f0.z >> 16),    acc[5]);
        acc[6] = fmaf(a0, bf2f(f0.w & 0xFFFF), acc[6]);
        acc[7] = fmaf(a0, bf2f(f0.w >> 16),    acc[7]);
        acc[0] = fmaf(a1, bf2f(f1.x & 0xFFFF), acc[0]);
        acc[1] = fmaf(a1, bf2f(f1.x >> 16),    acc[1]);
        acc[2] = fmaf(a1, bf2f(f1.y & 0xFFFF), acc[2]);
        acc[3] = fmaf(a1, bf2f(f1.y >> 16),    acc[3]);
        acc[4] = fmaf(a1, bf2f(f1.z & 0xFFFF), acc[4]);
        acc[5] = fmaf(a1, bf2f(f1.z >> 16),    acc[5]);
        acc[6] = fmaf(a1, bf2f(f1.w & 0xFFFF), acc[6]);
        acc[7] = fmaf(a1, bf2f(f1.w >> 16),    acc[7]);
    }
    if (e < end) {
        int sv = csr_src[e];
        float v = el[(size_t)sv * 4 + h0] + erh;
        v = (v >= 0.f) ? v : NEG_SLOPE * v;
        float a0 = __expf(v - mh) * rz;
        uint4 f0 = *(const uint4*)(featb + (size_t)sv * 128 + c0);
        acc[0] = fmaf(a0, bf2f(f0.x & 0xFFFF), acc[0]);
        acc[1] = fmaf(a0, bf2f(f0.x >> 16),    acc[1]);
        acc[2] = fmaf(a0, bf2f(f0.y & 0xFFFF), acc[2]);
        acc[3] = fmaf(a0, bf2f(f0.y >> 16),    acc[3]);
        acc[4] = fmaf(a0, bf2f(f0.z & 0xFFFF), acc[4]);
        acc[5] = fmaf(a0, bf2f(f0.z >> 16),    acc[5]);
        acc[6] = fmaf(a0, bf2f(f0.w & 0xFFFF), acc[6]);
        acc[7] = fmaf(a0, bf2f(f0.w >> 16),    acc[7]);
    }

    float4 b0 = *(const float4*)(bias + c0);
    float4 b1 = *(const float4*)(bias + c0 + 4);
    float4 o0, o1;
    o0.x = acc[0] + b0.x; o0.y = acc[1] + b0.y; o0.z = acc[2] + b0.z; o0.w = acc[3] + b0.w;
    o1.x = acc[4] + b1.x; o1.y = acc[5] + b1.y; o1.z = acc[6] + b1.z; o1.w = acc[7] + b1.w;
    *(float4*)(out + (size_t)n * 128 + c0) = o0;
    *(float4*)(out + (size_t)n * 128 + c0 + 4) = o1;
}

// ---------------------------------------------------------------------------
extern "C" void kernel_launch(void* const* d_in, const int* in_sizes, int n_in,
                              void* d_out, int out_size, void* d_ws, size_t ws_size,
                              hipStream_t stream) {
    const float* x   = (const float*)d_in[0];
    const int*   src = (const int*)d_in[1];
    const int*   dst = (const int*)d_in[2];
    const float* W1  = (const float*)d_in[3];
    const float* al1 = (const float*)d_in[4];
    const float* ar1 = (const float*)d_in[5];
    const float* b1  = (const float*)d_in[6];
    const float* W2  = (const float*)d_in[7];
    const float* al2 = (const float*)d_in[8];
    const float* ar2 = (const float*)d_in[9];
    const float* b2  = (const float*)d_in[10];
    const float* Wp  = (const float*)d_in[11];
    const float* bp  = (const float*)d_in[12];

    const int N = in_sizes[0] / F;      // 50000
    const int E = in_sizes[1];          // 800000

    float* h_out = (float*)d_out;               // [N,128]  (layer-2 output h)
    float* p_out = h_out + (size_t)N * F;       // [N,128]  (projection output)

    // workspace carve
    char* w = (char*)d_ws;
    ushort* featb   = (ushort*)w;                               // N*128 bf16
    float* el       = (float*)(w + (size_t)N * F * 2);          // N*4
    float* er       = el + (size_t)N * 4;                       // N*4
    int*   offs     = (int*)(er + (size_t)N * 4);               // N+1
    int*   counts   = offs + (N + 1);                           // N
    int*   rank     = counts + N;                               // E (becomes pos)
    int*   csrsrc   = rank + E;                                 // E
    int*   partials = csrsrc + E;                               // 256

    float* h1 = p_out;  // use d_out second half as layer-1 output scratch

    const int NB = (N + 255) / 256;
    const int EB = (E + 255) / 256;

    // --- CSR build (dst is identical for both layers) ---
    hipMemsetAsync(counts, 0, (size_t)N * 4, stream);
    rank_hist_kernel<<<EB, 256, 0, stream>>>(dst, counts, rank, E);
    scanA_kernel<<<NB, 256, 0, stream>>>(counts, offs, partials, N);
    scanB_kernel<<<1, 256, 0, stream>>>(partials, NB);
    scanC_kernel<<<NB, 256, 0, stream>>>(offs, partials, N, E);
    posfix_kernel<<<EB, 256, 0, stream>>>(dst, offs, rank, E);
    scatter_ranged_kernel<<<8 * ((E + SCH - 1) / SCH), 256, 0, stream>>>(src, rank, csrsrc, E);

    dim3 ggrid((N + 63) / 64, 2);
    int agrid = (N + 15) / 16;

    // --- layer 1 ---
    gemm_kernel<false, true><<<ggrid, 256, 0, stream>>>(x, W1, nullptr, featb, N);
    eler_kernel<<<(N * 4 + 255) / 256, 256, 0, stream>>>(featb, al1, ar1, el, er, N * 4);
    aggregate_kernel<<<agrid, 256, 0, stream>>>(featb, el, er, b1, offs, csrsrc, h1, N);

    // --- layer 2 ---
    gemm_kernel<false, true><<<ggrid, 256, 0, stream>>>(h1, W2, nullptr, featb, N);
    eler_kernel<<<(N * 4 + 255) / 256, 256, 0, stream>>>(featb, al2, ar2, el, er, N * 4);
    aggregate_kernel<<<agrid, 256, 0, stream>>>(featb, el, er, b2, offs, csrsrc, h_out, N);

    // --- projection (reads h_out fp32, writes fp32 + bias) ---
    gemm_kernel<true, false><<<ggrid, 256, 0, stream>>>(h_out, Wp, bp, p_out, N);
}

// Round 5
// 261.371 us; speedup vs baseline: 2.0883x; 1.1172x over previous
//
#include <hip/hip_runtime.h>
#include <hip/hip_bf16.h>

#define N_NODES 50000
#define HEADS 4
#define DHEAD 32
#define F 128           // HEADS*DHEAD = in/out feature width everywhere
#define NEG_SLOPE 0.2f

typedef unsigned int uint;
typedef unsigned short ushort;
typedef __attribute__((ext_vector_type(8))) short bf16x8;
typedef __attribute__((ext_vector_type(4))) float f32x4;

__device__ __forceinline__ float bf2f(ushort u) {
    union { uint i; float f; } c; c.i = ((uint)u) << 16; return c.f;
}
__device__ __forceinline__ ushort f2bf(float f) {
    union { float f; uint i; } c; c.f = f;
    uint u = c.i + 0x7FFF + ((c.i >> 16) & 1);   // round-to-nearest-even
    return (ushort)(u >> 16);
}

// ---------------------------------------------------------------------------
// CSR build: rank+hist -> hierarchical scan -> posfix -> range-split scatter
// ---------------------------------------------------------------------------
__global__ void rank_hist_kernel(const int* __restrict__ dst, int* __restrict__ counts,
                                 int* __restrict__ rank, int E) {
    int i = blockIdx.x * 256 + threadIdx.x;
    if (i < E) rank[i] = atomicAdd(&counts[dst[i]], 1);
}

__global__ __launch_bounds__(256) void scanA_kernel(const int* __restrict__ counts,
                                                    int* __restrict__ local_sc,
                                                    int* __restrict__ partials, int N) {
    int i = blockIdx.x * 256 + threadIdx.x;
    int v = (i < N) ? counts[i] : 0;
    int lane = threadIdx.x & 63;
    int w = threadIdx.x >> 6;
    int x = v;
#pragma unroll
    for (int off = 1; off < 64; off <<= 1) {
        int t = __shfl_up(x, off);
        if (lane >= off) x += t;
    }
    __shared__ int wsum[4];
    if (lane == 63) wsum[w] = x;
    __syncthreads();
    int wpre = 0;
#pragma unroll
    for (int k = 0; k < 4; k++)
        if (k < w) wpre += wsum[k];
    if (i < N) local_sc[i] = x - v + wpre;
    if (threadIdx.x == 255) partials[blockIdx.x] = wpre + x;
}

__global__ void scanB_kernel(int* __restrict__ partials, int NP) {
    int tid = threadIdx.x;
    int v = (tid < NP) ? partials[tid] : 0;
    int lane = tid & 63;
    int w = tid >> 6;
    int x = v;
#pragma unroll
    for (int off = 1; off < 64; off <<= 1) {
        int t = __shfl_up(x, off);
        if (lane >= off) x += t;
    }
    __shared__ int wsum[4];
    if (lane == 63) wsum[w] = x;
    __syncthreads();
    int wpre = 0;
#pragma unroll
    for (int k = 0; k < 4; k++)
        if (k < w) wpre += wsum[k];
    if (tid < NP) partials[tid] = x - v + wpre;
}

__global__ __launch_bounds__(256) void scanC_kernel(int* __restrict__ offs,
                                                    const int* __restrict__ partials,
                                                    int N, int E) {
    int i = blockIdx.x * 256 + threadIdx.x;
    if (i < N) offs[i] += partials[blockIdx.x];
    if (i == 0) offs[N] = E;
}

__global__ void posfix_kernel(const int* __restrict__ dst, const int* __restrict__ offs,
                              int* __restrict__ rank, int E) {
    int i = blockIdx.x * 256 + threadIdx.x;
    if (i < E) rank[i] += offs[dst[i]];
}

#define SCH 2048   // edges per block chunk
__global__ __launch_bounds__(256) void scatter_ranged_kernel(
    const int* __restrict__ src, const int* __restrict__ pos,
    int* __restrict__ csr_src, int E) {
    int range = blockIdx.x & 7;
    int chunk = blockIdx.x >> 3;
    int base = chunk * SCH + threadIdx.x;
    int lo = (int)(((long long)range * E) >> 3);
    int hi = (int)(((long long)(range + 1) * E) >> 3);
#pragma unroll
    for (int k = 0; k < SCH / 256; k++) {
        int i = base + k * 256;
        if (i < E) {
            int p = pos[i];
            if (p >= lo && p < hi) csr_src[p] = src[i];
        }
    }
}

// ---------------------------------------------------------------------------
// Weight transpose + bf16 convert: WT[n][k] = bf16(W[k][n]). One block per
// matrix (128x128), blockIdx.x in {0,1,2}.
// ---------------------------------------------------------------------------
__global__ __launch_bounds__(256) void wtrans_kernel(const float* __restrict__ W1,
                                                     const float* __restrict__ W2,
                                                     const float* __restrict__ Wp,
                                                     ushort* __restrict__ WT) {
    const float* W = (blockIdx.x == 0) ? W1 : (blockIdx.x == 1) ? W2 : Wp;
    ushort* T = WT + (size_t)blockIdx.x * 128 * 128;
    for (int i = threadIdx.x; i < 128 * 128; i += 256) {
        int r = i >> 7, c = i & 127;
        T[c * 128 + r] = f2bf(W[i]);
    }
}

// ---------------------------------------------------------------------------
// MFMA GEMM: C[M,128] = A[M,128] @ B[128,128], B given transposed bf16
// (BT[n][k]). Block = 4 waves, each wave does 16 rows x 128 cols.
// A fragments: lane holds A[row0+(l&15)][ (l>>4)*8 + j ] per k-step.
// B fragments: lane holds BT[ct*16+(l&15)][ks*32+(l>>4)*8 + j].
// C/D: col = ct*16+(l&15), row = row0+(l>>4)*4+reg.
// ---------------------------------------------------------------------------
template <bool A_FP32, bool OUT_BF16, bool BIAS>
__global__ __launch_bounds__(256) void mfma_gemm_kernel(
    const void* __restrict__ Av, const ushort* __restrict__ BT,
    const float* __restrict__ bias, void* __restrict__ Cv, int M) {
    int wid = threadIdx.x >> 6;
    int lane = threadIdx.x & 63;
    int row0 = blockIdx.x * 64 + wid * 16;
    int rsub = lane & 15;
    int kg = lane >> 4;
    int row = row0 + rsub;
    int rowc = (row < M) ? row : (M - 1);

    bf16x8 af[4];
    if (A_FP32) {
        const float* A = (const float*)Av;
        const float* ap = A + (size_t)rowc * 128 + kg * 8;
#pragma unroll
        for (int ks = 0; ks < 4; ks++) {
            float4 lo = *(const float4*)(ap + ks * 32);
            float4 hi = *(const float4*)(ap + ks * 32 + 4);
            bf16x8 v;
            v[0] = (short)f2bf(lo.x); v[1] = (short)f2bf(lo.y);
            v[2] = (short)f2bf(lo.z); v[3] = (short)f2bf(lo.w);
            v[4] = (short)f2bf(hi.x); v[5] = (short)f2bf(hi.y);
            v[6] = (short)f2bf(hi.z); v[7] = (short)f2bf(hi.w);
            af[ks] = v;
        }
    } else {
        const ushort* A = (const ushort*)Av;
        const ushort* ap = A + (size_t)rowc * 128 + kg * 8;
#pragma unroll
        for (int ks = 0; ks < 4; ks++) af[ks] = *(const bf16x8*)(ap + ks * 32);
    }

    f32x4 acc[8];
#pragma unroll
    for (int ct = 0; ct < 8; ct++) acc[ct] = (f32x4){0.f, 0.f, 0.f, 0.f};

    const ushort* bp = BT + (size_t)rsub * 128 + kg * 8;
#pragma unroll
    for (int ks = 0; ks < 4; ks++) {
#pragma unroll
        for (int ct = 0; ct < 8; ct++) {
            bf16x8 bf = *(const bf16x8*)(bp + (size_t)ct * 16 * 128 + ks * 32);
            acc[ct] = __builtin_amdgcn_mfma_f32_16x16x32_bf16(af[ks], bf, acc[ct], 0, 0, 0);
        }
    }

    if (row0 >= M) return;
#pragma unroll
    for (int ct = 0; ct < 8; ct++) {
        int col = ct * 16 + rsub;
        float bv = BIAS ? bias[col] : 0.f;
#pragma unroll
        for (int r = 0; r < 4; r++) {
            int gr = row0 + kg * 4 + r;
            if (gr < M) {
                float v = acc[ct][r] + bv;
                if (OUT_BF16) ((ushort*)Cv)[(size_t)gr * 128 + col] = f2bf(v);
                else          ((float*)Cv)[(size_t)gr * 128 + col] = v;
            }
        }
    }
}

// ---------------------------------------------------------------------------
// el/er from bf16 feat: per (node,head) dot with al[h,:], ar[h,:]
// ---------------------------------------------------------------------------
__global__ void eler_kernel(const ushort* __restrict__ featb, const float* __restrict__ al,
                            const float* __restrict__ ar, float* __restrict__ el,
                            float* __restrict__ er, int NH) {
    int idx = blockIdx.x * 256 + threadIdx.x;
    if (idx >= NH) return;
    int h = idx & 3;
    const ushort* f = featb + (size_t)idx * 32;
    const float* a_l = al + h * 32;
    const float* a_r = ar + h * 32;
    float sl = 0.f, sr = 0.f;
#pragma unroll
    for (int q = 0; q < 4; q++) {
        uint4 fv = *(const uint4*)(f + q * 8);
        float fx[8] = {bf2f(fv.x & 0xFFFF), bf2f(fv.x >> 16),
                       bf2f(fv.y & 0xFFFF), bf2f(fv.y >> 16),
                       bf2f(fv.z & 0xFFFF), bf2f(fv.z >> 16),
                       bf2f(fv.w & 0xFFFF), bf2f(fv.w >> 16)};
        float4 lv0 = *(const float4*)(a_l + q * 8);
        float4 lv1 = *(const float4*)(a_l + q * 8 + 4);
        float4 rv0 = *(const float4*)(a_r + q * 8);
        float4 rv1 = *(const float4*)(a_r + q * 8 + 4);
        sl += fx[0] * lv0.x + fx[1] * lv0.y + fx[2] * lv0.z + fx[3] * lv0.w
            + fx[4] * lv1.x + fx[5] * lv1.y + fx[6] * lv1.z + fx[7] * lv1.w;
        sr += fx[0] * rv0.x + fx[1] * rv0.y + fx[2] * rv0.z + fx[3] * rv0.w
            + fx[4] * rv1.x + fx[5] * rv1.y + fx[6] * rv1.z + fx[7] * rv1.w;
    }
    el[idx] = sl;
    er[idx] = sr;
}

// ---------------------------------------------------------------------------
// Aggregate: 16 lanes per node (4 nodes per wave). Pass1 online-softmax over
// edges (lane-parallel), 4-step xor reduce. Pass2 serial edge loop, each lane
// owns 8 columns = one 16B bf16 load per edge. Output: fp32 (outf) and/or
// bf16 (outb) copies.
// ---------------------------------------------------------------------------
__global__ __launch_bounds__(256) void aggregate_kernel(
    const ushort* __restrict__ featb, const float* __restrict__ el,
    const float* __restrict__ er, const float* __restrict__ bias,
    const int* __restrict__ offsets, const int* __restrict__ csr_src,
    float* __restrict__ outf, ushort* __restrict__ outb, int N) {
    int tid = threadIdx.x;
    int gl = tid & 15;
    int n = blockIdx.x * 16 + (tid >> 4);
    if (n >= N) return;
    int start = offsets[n], end = offsets[n + 1];

    float4 erv = *(const float4*)(er + (size_t)n * 4);
    float er_h[4] = {erv.x, erv.y, erv.z, erv.w};

    float m[4], s[4];
#pragma unroll
    for (int h = 0; h < 4; h++) { m[h] = -1e30f; s[h] = 0.f; }

    for (int e = start + gl; e < end; e += 16) {
        int sv = csr_src[e];
        float4 ev = *(const float4*)(el + (size_t)sv * 4);
        float elh[4] = {ev.x, ev.y, ev.z, ev.w};
#pragma unroll
        for (int h = 0; h < 4; h++) {
            float v = elh[h] + er_h[h];
            v = (v >= 0.f) ? v : NEG_SLOPE * v;
            float mn = fmaxf(m[h], v);
            s[h] = s[h] * __expf(m[h] - mn) + __expf(v - mn);
            m[h] = mn;
        }
    }
#pragma unroll
    for (int off = 1; off < 16; off <<= 1) {
#pragma unroll
        for (int h = 0; h < 4; h++) {
            float mo = __shfl_xor(m[h], off);
            float so = __shfl_xor(s[h], off);
            float mn = fmaxf(m[h], mo);
            s[h] = s[h] * __expf(m[h] - mn) + so * __expf(mo - mn);
            m[h] = mn;
        }
    }

    int h0 = gl >> 2;
    int c0 = gl * 8;
    float mh  = (h0 < 2) ? (h0 == 0 ? m[0] : m[1]) : (h0 == 2 ? m[2] : m[3]);
    float sh  = (h0 < 2) ? (h0 == 0 ? s[0] : s[1]) : (h0 == 2 ? s[2] : s[3]);
    float erh = (h0 < 2) ? (h0 == 0 ? er_h[0] : er_h[1]) : (h0 == 2 ? er_h[2] : er_h[3]);
    float rz = (end > start) ? 1.0f / sh : 0.f;

    float acc[8] = {};
    int e = start;
    for (; e + 1 < end; e += 2) {
        int sv0 = csr_src[e];
        int sv1 = csr_src[e + 1];
        float v0 = el[(size_t)sv0 * 4 + h0] + erh;
        float v1 = el[(size_t)sv1 * 4 + h0] + erh;
        v0 = (v0 >= 0.f) ? v0 : NEG_SLOPE * v0;
        v1 = (v1 >= 0.f) ? v1 : NEG_SLOPE * v1;
        float a0 = __expf(v0 - mh) * rz;
        float a1 = __expf(v1 - mh) * rz;
        uint4 f0 = *(const uint4*)(featb + (size_t)sv0 * 128 + c0);
        uint4 f1 = *(const uint4*)(featb + (size_t)sv1 * 128 + c0);
        acc[0] = fmaf(a0, bf2f(f0.x & 0xFFFF), acc[0]);
        acc[1] = fmaf(a0, bf2f(f0.x >> 16),    acc[1]);
        acc[2] = fmaf(a0, bf2f(f0.y & 0xFFFF), acc[2]);
        acc[3] = fmaf(a0, bf2f(f0.y >> 16),    acc[3]);
        acc[4] = fmaf(a0, bf2f(f0.z & 0xFFFF), acc[4]);
        acc[5] = fmaf(a0, bf2f(f0.z >> 16),    acc[5]);
        acc[6] = fmaf(a0, bf2f(f0.w & 0xFFFF), acc[6]);
        acc[7] = fmaf(a0, bf2f(f0.w >> 16),    acc[7]);
        acc[0] = fmaf(a1, bf2f(f1.x & 0xFFFF), acc[0]);
        acc[1] = fmaf(a1, bf2f(f1.x >> 16),    acc[1]);
        acc[2] = fmaf(a1, bf2f(f1.y & 0xFFFF), acc[2]);
        acc[3] = fmaf(a1, bf2f(f1.y >> 16),    acc[3]);
        acc[4] = fmaf(a1, bf2f(f1.z & 0xFFFF), acc[4]);
        acc[5] = fmaf(a1, bf2f(f1.z >> 16),    acc[5]);
        acc[6] = fmaf(a1, bf2f(f1.w & 0xFFFF), acc[6]);
        acc[7] = fmaf(a1, bf2f(f1.w >> 16),    acc[7]);
    }
    if (e < end) {
        int sv = csr_src[e];
        float v = el[(size_t)sv * 4 + h0] + erh;
        v = (v >= 0.f) ? v : NEG_SLOPE * v;
        float a0 = __expf(v - mh) * rz;
        uint4 f0 = *(const uint4*)(featb + (size_t)sv * 128 + c0);
        acc[0] = fmaf(a0, bf2f(f0.x & 0xFFFF), acc[0]);
        acc[1] = fmaf(a0, bf2f(f0.x >> 16),    acc[1]);
        acc[2] = fmaf(a0, bf2f(f0.y & 0xFFFF), acc[2]);
        acc[3] = fmaf(a0, bf2f(f0.y >> 16),    acc[3]);
        acc[4] = fmaf(a0, bf2f(f0.z & 0xFFFF), acc[4]);
        acc[5] = fmaf(a0, bf2f(f0.z >> 16),    acc[5]);
        acc[6] = fmaf(a0, bf2f(f0.w & 0xFFFF), acc[6]);
        acc[7] = fmaf(a0, bf2f(f0.w >> 16),    acc[7]);
    }

    float4 b0 = *(const float4*)(bias + c0);
    float4 b1 = *(const float4*)(bias + c0 + 4);
    float o[8];
    o[0] = acc[0] + b0.x; o[1] = acc[1] + b0.y; o[2] = acc[2] + b0.z; o[3] = acc[3] + b0.w;
    o[4] = acc[4] + b1.x; o[5] = acc[5] + b1.y; o[6] = acc[6] + b1.z; o[7] = acc[7] + b1.w;
    if (outf) {
        float4 w0, w1;
        w0.x = o[0]; w0.y = o[1]; w0.z = o[2]; w0.w = o[3];
        w1.x = o[4]; w1.y = o[5]; w1.z = o[6]; w1.w = o[7];
        *(float4*)(outf + (size_t)n * 128 + c0) = w0;
        *(float4*)(outf + (size_t)n * 128 + c0 + 4) = w1;
    }
    if (outb) {
        uint4 p;
        p.x = (uint)f2bf(o[0]) | ((uint)f2bf(o[1]) << 16);
        p.y = (uint)f2bf(o[2]) | ((uint)f2bf(o[3]) << 16);
        p.z = (uint)f2bf(o[4]) | ((uint)f2bf(o[5]) << 16);
        p.w = (uint)f2bf(o[6]) | ((uint)f2bf(o[7]) << 16);
        *(uint4*)(outb + (size_t)n * 128 + c0) = p;
    }
}

// ---------------------------------------------------------------------------
extern "C" void kernel_launch(void* const* d_in, const int* in_sizes, int n_in,
                              void* d_out, int out_size, void* d_ws, size_t ws_size,
                              hipStream_t stream) {
    const float* x   = (const float*)d_in[0];
    const int*   src = (const int*)d_in[1];
    const int*   dst = (const int*)d_in[2];
    const float* W1  = (const float*)d_in[3];
    const float* al1 = (const float*)d_in[4];
    const float* ar1 = (const float*)d_in[5];
    const float* b1  = (const float*)d_in[6];
    const float* W2  = (const float*)d_in[7];
    const float* al2 = (const float*)d_in[8];
    const float* ar2 = (const float*)d_in[9];
    const float* b2  = (const float*)d_in[10];
    const float* Wp  = (const float*)d_in[11];
    const float* bp  = (const float*)d_in[12];

    const int N = in_sizes[0] / F;      // 50000
    const int E = in_sizes[1];          // 800000

    float* h_out = (float*)d_out;               // [N,128]  (layer-2 output h, checked)
    float* p_out = h_out + (size_t)N * F;       // [N,128]  (projection output, checked)

    // workspace carve
    char* w = (char*)d_ws;
    ushort* featb   = (ushort*)w;                               // N*128 bf16
    ushort* h1b     = featb + (size_t)N * F;                    // N*128 bf16 (also hb)
    float* el       = (float*)(h1b + (size_t)N * F);            // N*4
    float* er       = el + (size_t)N * 4;                       // N*4
    int*   offs     = (int*)(er + (size_t)N * 4);               // N+1
    int*   counts   = offs + (N + 1);                           // N
    int*   rank     = counts + N;                               // E (becomes pos)
    int*   csrsrc   = rank + E;                                 // E
    int*   partials = csrsrc + E;                               // 256
    ushort* WT      = (ushort*)(partials + 256);                // 3*128*128 bf16

    const int NB = (N + 255) / 256;
    const int EB = (E + 255) / 256;

    // --- CSR build (dst is identical for both layers) ---
    hipMemsetAsync(counts, 0, (size_t)N * 4, stream);
    rank_hist_kernel<<<EB, 256, 0, stream>>>(dst, counts, rank, E);
    scanA_kernel<<<NB, 256, 0, stream>>>(counts, offs, partials, N);
    scanB_kernel<<<1, 256, 0, stream>>>(partials, NB);
    scanC_kernel<<<NB, 256, 0, stream>>>(offs, partials, N, E);
    posfix_kernel<<<EB, 256, 0, stream>>>(dst, offs, rank, E);
    scatter_ranged_kernel<<<8 * ((E + SCH - 1) / SCH), 256, 0, stream>>>(src, rank, csrsrc, E);

    // --- weight transposes (bf16) ---
    wtrans_kernel<<<3, 256, 0, stream>>>(W1, W2, Wp, WT);
    ushort* WT1 = WT;
    ushort* WT2 = WT + 128 * 128;
    ushort* WTp = WT + 2 * 128 * 128;

    int ggrid = (N + 63) / 64;
    int agrid = (N + 15) / 16;

    // --- layer 1 ---
    mfma_gemm_kernel<true, true, false><<<ggrid, 256, 0, stream>>>(x, WT1, nullptr, featb, N);
    eler_kernel<<<(N * 4 + 255) / 256, 256, 0, stream>>>(featb, al1, ar1, el, er, N * 4);
    aggregate_kernel<<<agrid, 256, 0, stream>>>(featb, el, er, b1, offs, csrsrc, nullptr, h1b, N);

    // --- layer 2 ---
    mfma_gemm_kernel<false, true, false><<<ggrid, 256, 0, stream>>>(h1b, WT2, nullptr, featb, N);
    eler_kernel<<<(N * 4 + 255) / 256, 256, 0, stream>>>(featb, al2, ar2, el, er, N * 4);
    aggregate_kernel<<<agrid, 256, 0, stream>>>(featb, el, er, b2, offs, csrsrc, h_out, h1b, N);

    // --- projection (reads bf16 h copy, writes fp32 + bias) ---
    mfma_gemm_kernel<false, false, true><<<ggrid, 256, 0, stream>>>(h1b, WTp, bp, p_out, N);
}

// Round 6
// 254.060 us; speedup vs baseline: 2.1484x; 1.0288x over previous
//
#include <hip/hip_runtime.h>
#include <hip/hip_bf16.h>

#define N_NODES 50000
#define HEADS 4
#define DHEAD 32
#define F 128           // HEADS*DHEAD = in/out feature width everywhere
#define NEG_SLOPE 0.2f

typedef unsigned int uint;
typedef unsigned short ushort;
typedef __attribute__((ext_vector_type(8))) short bf16x8;
typedef __attribute__((ext_vector_type(4))) float f32x4;

__device__ __forceinline__ float bf2f(ushort u) {
    union { uint i; float f; } c; c.i = ((uint)u) << 16; return c.f;
}
__device__ __forceinline__ ushort f2bf(float f) {
    union { float f; uint i; } c; c.f = f;
    uint u = c.i + 0x7FFF + ((c.i >> 16) & 1);   // round-to-nearest-even
    return (ushort)(u >> 16);
}

// ---------------------------------------------------------------------------
// CSR build: rank+hist -> hierarchical scan -> posfix -> range-split scatter
// ---------------------------------------------------------------------------
__global__ void rank_hist_kernel(const int* __restrict__ dst, int* __restrict__ counts,
                                 int* __restrict__ rank, int E) {
    int i = blockIdx.x * 256 + threadIdx.x;
    if (i < E) rank[i] = atomicAdd(&counts[dst[i]], 1);
}

__global__ __launch_bounds__(256) void scanA_kernel(const int* __restrict__ counts,
                                                    int* __restrict__ local_sc,
                                                    int* __restrict__ partials, int N) {
    int i = blockIdx.x * 256 + threadIdx.x;
    int v = (i < N) ? counts[i] : 0;
    int lane = threadIdx.x & 63;
    int w = threadIdx.x >> 6;
    int x = v;
#pragma unroll
    for (int off = 1; off < 64; off <<= 1) {
        int t = __shfl_up(x, off);
        if (lane >= off) x += t;
    }
    __shared__ int wsum[4];
    if (lane == 63) wsum[w] = x;
    __syncthreads();
    int wpre = 0;
#pragma unroll
    for (int k = 0; k < 4; k++)
        if (k < w) wpre += wsum[k];
    if (i < N) local_sc[i] = x - v + wpre;
    if (threadIdx.x == 255) partials[blockIdx.x] = wpre + x;
}

__global__ void scanB_kernel(int* __restrict__ partials, int NP) {
    int tid = threadIdx.x;
    int v = (tid < NP) ? partials[tid] : 0;
    int lane = tid & 63;
    int w = tid >> 6;
    int x = v;
#pragma unroll
    for (int off = 1; off < 64; off <<= 1) {
        int t = __shfl_up(x, off);
        if (lane >= off) x += t;
    }
    __shared__ int wsum[4];
    if (lane == 63) wsum[w] = x;
    __syncthreads();
    int wpre = 0;
#pragma unroll
    for (int k = 0; k < 4; k++)
        if (k < w) wpre += wsum[k];
    if (tid < NP) partials[tid] = x - v + wpre;
}

__global__ __launch_bounds__(256) void scanC_kernel(int* __restrict__ offs,
                                                    const int* __restrict__ partials,
                                                    int N, int E) {
    int i = blockIdx.x * 256 + threadIdx.x;
    if (i < N) offs[i] += partials[blockIdx.x];
    if (i == 0) offs[N] = E;
}

__global__ void posfix_kernel(const int* __restrict__ dst, const int* __restrict__ offs,
                              int* __restrict__ rank, int E) {
    int i = blockIdx.x * 256 + threadIdx.x;
    if (i < E) rank[i] += offs[dst[i]];
}

#define SCH 2048   // edges per block chunk
__global__ __launch_bounds__(256) void scatter_ranged_kernel(
    const int* __restrict__ src, const int* __restrict__ pos,
    int* __restrict__ csr_src, int E) {
    int range = blockIdx.x & 7;
    int chunk = blockIdx.x >> 3;
    int base = chunk * SCH + threadIdx.x;
    int lo = (int)(((long long)range * E) >> 3);
    int hi = (int)(((long long)(range + 1) * E) >> 3);
#pragma unroll
    for (int k = 0; k < SCH / 256; k++) {
        int i = base + k * 256;
        if (i < E) {
            int p = pos[i];
            if (p >= lo && p < hi) csr_src[p] = src[i];
        }
    }
}

// ---------------------------------------------------------------------------
// Weight transpose + bf16 convert: WT[n][k] = bf16(W[k][n]).
// ---------------------------------------------------------------------------
__global__ __launch_bounds__(256) void wtrans_kernel(const float* __restrict__ W1,
                                                     const float* __restrict__ W2,
                                                     const float* __restrict__ Wp,
                                                     ushort* __restrict__ WT) {
    const float* W = (blockIdx.x == 0) ? W1 : (blockIdx.x == 1) ? W2 : Wp;
    ushort* T = WT + (size_t)blockIdx.x * 128 * 128;
    for (int i = threadIdx.x; i < 128 * 128; i += 256) {
        int r = i >> 7, c = i & 127;
        T[c * 128 + r] = f2bf(W[i]);
    }
}

// ---------------------------------------------------------------------------
// MFMA GEMM: C[M,128] = A[M,128] @ B[128,128], B transposed bf16 (BT[n][k]).
// Block = 4 waves, each wave 16 rows x 128 cols.
// ---------------------------------------------------------------------------
template <bool A_FP32, bool OUT_BF16, bool BIAS>
__global__ __launch_bounds__(256) void mfma_gemm_kernel(
    const void* __restrict__ Av, const ushort* __restrict__ BT,
    const float* __restrict__ bias, void* __restrict__ Cv, int M) {
    int wid = threadIdx.x >> 6;
    int lane = threadIdx.x & 63;
    int row0 = blockIdx.x * 64 + wid * 16;
    int rsub = lane & 15;
    int kg = lane >> 4;
    int row = row0 + rsub;
    int rowc = (row < M) ? row : (M - 1);

    bf16x8 af[4];
    if (A_FP32) {
        const float* A = (const float*)Av;
        const float* ap = A + (size_t)rowc * 128 + kg * 8;
#pragma unroll
        for (int ks = 0; ks < 4; ks++) {
            float4 lo = *(const float4*)(ap + ks * 32);
            float4 hi = *(const float4*)(ap + ks * 32 + 4);
            bf16x8 v;
            v[0] = (short)f2bf(lo.x); v[1] = (short)f2bf(lo.y);
            v[2] = (short)f2bf(lo.z); v[3] = (short)f2bf(lo.w);
            v[4] = (short)f2bf(hi.x); v[5] = (short)f2bf(hi.y);
            v[6] = (short)f2bf(hi.z); v[7] = (short)f2bf(hi.w);
            af[ks] = v;
        }
    } else {
        const ushort* A = (const ushort*)Av;
        const ushort* ap = A + (size_t)rowc * 128 + kg * 8;
#pragma unroll
        for (int ks = 0; ks < 4; ks++) af[ks] = *(const bf16x8*)(ap + ks * 32);
    }

    f32x4 acc[8];
#pragma unroll
    for (int ct = 0; ct < 8; ct++) acc[ct] = (f32x4){0.f, 0.f, 0.f, 0.f};

    const ushort* bp = BT + (size_t)rsub * 128 + kg * 8;
#pragma unroll
    for (int ks = 0; ks < 4; ks++) {
#pragma unroll
        for (int ct = 0; ct < 8; ct++) {
            bf16x8 bf = *(const bf16x8*)(bp + (size_t)ct * 16 * 128 + ks * 32);
            acc[ct] = __builtin_amdgcn_mfma_f32_16x16x32_bf16(af[ks], bf, acc[ct], 0, 0, 0);
        }
    }

    if (row0 >= M) return;
#pragma unroll
    for (int ct = 0; ct < 8; ct++) {
        int col = ct * 16 + rsub;
        float bv = BIAS ? bias[col] : 0.f;
#pragma unroll
        for (int r = 0; r < 4; r++) {
            int gr = row0 + kg * 4 + r;
            if (gr < M) {
                float v = acc[ct][r] + bv;
                if (OUT_BF16) ((ushort*)Cv)[(size_t)gr * 128 + col] = f2bf(v);
                else          ((float*)Cv)[(size_t)gr * 128 + col] = v;
            }
        }
    }
}

// ---------------------------------------------------------------------------
// el/er from bf16 feat
// ---------------------------------------------------------------------------
__global__ void eler_kernel(const ushort* __restrict__ featb, const float* __restrict__ al,
                            const float* __restrict__ ar, float* __restrict__ el,
                            float* __restrict__ er, int NH) {
    int idx = blockIdx.x * 256 + threadIdx.x;
    if (idx >= NH) return;
    int h = idx & 3;
    const ushort* f = featb + (size_t)idx * 32;
    const float* a_l = al + h * 32;
    const float* a_r = ar + h * 32;
    float sl = 0.f, sr = 0.f;
#pragma unroll
    for (int q = 0; q < 4; q++) {
        uint4 fv = *(const uint4*)(f + q * 8);
        float fx[8] = {bf2f(fv.x & 0xFFFF), bf2f(fv.x >> 16),
                       bf2f(fv.y & 0xFFFF), bf2f(fv.y >> 16),
                       bf2f(fv.z & 0xFFFF), bf2f(fv.z >> 16),
                       bf2f(fv.w & 0xFFFF), bf2f(fv.w >> 16)};
        float4 lv0 = *(const float4*)(a_l + q * 8);
        float4 lv1 = *(const float4*)(a_l + q * 8 + 4);
        float4 rv0 = *(const float4*)(a_r + q * 8);
        float4 rv1 = *(const float4*)(a_r + q * 8 + 4);
        sl += fx[0] * lv0.x + fx[1] * lv0.y + fx[2] * lv0.z + fx[3] * lv0.w
            + fx[4] * lv1.x + fx[5] * lv1.y + fx[6] * lv1.z + fx[7] * lv1.w;
        sr += fx[0] * rv0.x + fx[1] * rv0.y + fx[2] * rv0.z + fx[3] * rv0.w
            + fx[4] * rv1.x + fx[5] * rv1.y + fx[6] * rv1.z + fx[7] * rv1.w;
    }
    el[idx] = sl;
    er[idx] = sr;
}

// ---------------------------------------------------------------------------
// Aggregate: 16 lanes per node (4 nodes/wave). Pass1 online-softmax.
// Pass2: 4-edge batches; lane (j=gl&3, h=gl>>2) computes alpha(edge j, head h)
// once; sv/alpha shared via shfl; 4 independent 16B featb loads per batch.
// F32OUT: write fp32 out; else write bf16 out.
// ---------------------------------------------------------------------------
template <bool F32OUT>
__global__ __launch_bounds__(256) void aggregate_kernel(
    const ushort* __restrict__ featb, const float* __restrict__ el,
    const float* __restrict__ er, const float* __restrict__ bias,
    const int* __restrict__ offsets, const int* __restrict__ csr_src,
    void* __restrict__ outv, int N) {
    int tid = threadIdx.x;
    int gl = tid & 15;
    int lane = tid & 63;
    int n = blockIdx.x * 16 + (tid >> 4);
    if (n >= N) return;
    int start = offsets[n], end = offsets[n + 1];

    float4 erv = *(const float4*)(er + (size_t)n * 4);
    float er_h[4] = {erv.x, erv.y, erv.z, erv.w};

    float m[4], s[4];
#pragma unroll
    for (int h = 0; h < 4; h++) { m[h] = -1e30f; s[h] = 0.f; }

    for (int e = start + gl; e < end; e += 16) {
        int sv = csr_src[e];
        float4 ev = *(const float4*)(el + (size_t)sv * 4);
        float elh[4] = {ev.x, ev.y, ev.z, ev.w};
#pragma unroll
        for (int h = 0; h < 4; h++) {
            float v = elh[h] + er_h[h];
            v = (v >= 0.f) ? v : NEG_SLOPE * v;
            float mn = fmaxf(m[h], v);
            s[h] = s[h] * __expf(m[h] - mn) + __expf(v - mn);
            m[h] = mn;
        }
    }
#pragma unroll
    for (int off = 1; off < 16; off <<= 1) {
#pragma unroll
        for (int h = 0; h < 4; h++) {
            float mo = __shfl_xor(m[h], off);
            float so = __shfl_xor(s[h], off);
            float mn = fmaxf(m[h], mo);
            s[h] = s[h] * __expf(m[h] - mn) + so * __expf(mo - mn);
            m[h] = mn;
        }
    }

    int h0 = gl >> 2;                 // head of my 8 columns AND my alpha slot
    int j  = gl & 3;                  // my edge slot within a 4-edge batch
    int c0 = gl * 8;
    float mh  = (h0 & 2) ? ((h0 & 1) ? m[3] : m[2]) : ((h0 & 1) ? m[1] : m[0]);
    float sh  = (h0 & 2) ? ((h0 & 1) ? s[3] : s[2]) : ((h0 & 1) ? s[1] : s[0]);
    float erh = (h0 & 2) ? ((h0 & 1) ? er_h[3] : er_h[2]) : ((h0 & 1) ? er_h[1] : er_h[0]);
    float rzh = (end > start) ? 1.0f / sh : 0.f;
    int bidx = lane & 60;             // group base | h0<<2 (source lanes for shfl)

    float acc[8] = {};
    for (int e = start; e < end; e += 4) {
        int rem = end - e;
        int ej = e + ((j < rem) ? j : 0);
        int svj = csr_src[ej];
        float v = el[(size_t)svj * 4 + h0] + erh;
        v = (v >= 0.f) ? v : NEG_SLOPE * v;
        float a = __expf(v - mh) * rzh;
        if (j >= rem) a = 0.f;
#pragma unroll
        for (int jj = 0; jj < 4; jj++) {
            float ajj = __shfl(a, bidx | jj);
            int svjj  = __shfl(svj, bidx | jj);
            uint4 f0 = *(const uint4*)(featb + (size_t)svjj * 128 + c0);
            acc[0] = fmaf(ajj, bf2f(f0.x & 0xFFFF), acc[0]);
            acc[1] = fmaf(ajj, bf2f(f0.x >> 16),    acc[1]);
            acc[2] = fmaf(ajj, bf2f(f0.y & 0xFFFF), acc[2]);
            acc[3] = fmaf(ajj, bf2f(f0.y >> 16),    acc[3]);
            acc[4] = fmaf(ajj, bf2f(f0.z & 0xFFFF), acc[4]);
            acc[5] = fmaf(ajj, bf2f(f0.z >> 16),    acc[5]);
            acc[6] = fmaf(ajj, bf2f(f0.w & 0xFFFF), acc[6]);
            acc[7] = fmaf(ajj, bf2f(f0.w >> 16),    acc[7]);
        }
    }

    float4 b0 = *(const float4*)(bias + c0);
    float4 b1 = *(const float4*)(bias + c0 + 4);
    float o[8];
    o[0] = acc[0] + b0.x; o[1] = acc[1] + b0.y; o[2] = acc[2] + b0.z; o[3] = acc[3] + b0.w;
    o[4] = acc[4] + b1.x; o[5] = acc[5] + b1.y; o[6] = acc[6] + b1.z; o[7] = acc[7] + b1.w;
    if (F32OUT) {
        float* outf = (float*)outv;
        float4 w0, w1;
        w0.x = o[0]; w0.y = o[1]; w0.z = o[2]; w0.w = o[3];
        w1.x = o[4]; w1.y = o[5]; w1.z = o[6]; w1.w = o[7];
        *(float4*)(outf + (size_t)n * 128 + c0) = w0;
        *(float4*)(outf + (size_t)n * 128 + c0 + 4) = w1;
    } else {
        ushort* outb = (ushort*)outv;
        uint4 p;
        p.x = (uint)f2bf(o[0]) | ((uint)f2bf(o[1]) << 16);
        p.y = (uint)f2bf(o[2]) | ((uint)f2bf(o[3]) << 16);
        p.z = (uint)f2bf(o[4]) | ((uint)f2bf(o[5]) << 16);
        p.w = (uint)f2bf(o[6]) | ((uint)f2bf(o[7]) << 16);
        *(uint4*)(outb + (size_t)n * 128 + c0) = p;
    }
}

// ---------------------------------------------------------------------------
extern "C" void kernel_launch(void* const* d_in, const int* in_sizes, int n_in,
                              void* d_out, int out_size, void* d_ws, size_t ws_size,
                              hipStream_t stream) {
    const float* x   = (const float*)d_in[0];
    const int*   src = (const int*)d_in[1];
    const int*   dst = (const int*)d_in[2];
    const float* W1  = (const float*)d_in[3];
    const float* al1 = (const float*)d_in[4];
    const float* ar1 = (const float*)d_in[5];
    const float* b1  = (const float*)d_in[6];
    const float* W2  = (const float*)d_in[7];
    const float* al2 = (const float*)d_in[8];
    const float* ar2 = (const float*)d_in[9];
    const float* b2  = (const float*)d_in[10];
    const float* Wp  = (const float*)d_in[11];
    const float* bp  = (const float*)d_in[12];

    const int N = in_sizes[0] / F;      // 50000
    const int E = in_sizes[1];          // 800000

    float* h_out = (float*)d_out;               // [N,128]  (layer-2 output h, checked)
    float* p_out = h_out + (size_t)N * F;       // [N,128]  (projection output, checked)

    // workspace carve
    char* w = (char*)d_ws;
    ushort* featb   = (ushort*)w;                               // N*128 bf16
    ushort* h1b     = featb + (size_t)N * F;                    // N*128 bf16
    float* el       = (float*)(h1b + (size_t)N * F);            // N*4
    float* er       = el + (size_t)N * 4;                       // N*4
    int*   offs     = (int*)(er + (size_t)N * 4);               // N+1
    int*   counts   = offs + (N + 1);                           // N
    int*   rank     = counts + N;                               // E (becomes pos)
    int*   csrsrc   = rank + E;                                 // E
    int*   partials = csrsrc + E;                               // 256
    ushort* WT      = (ushort*)(partials + 256);                // 3*128*128 bf16

    const int NB = (N + 255) / 256;
    const int EB = (E + 255) / 256;

    // --- CSR build (dst is identical for both layers) ---
    hipMemsetAsync(counts, 0, (size_t)N * 4, stream);
    rank_hist_kernel<<<EB, 256, 0, stream>>>(dst, counts, rank, E);
    scanA_kernel<<<NB, 256, 0, stream>>>(counts, offs, partials, N);
    scanB_kernel<<<1, 256, 0, stream>>>(partials, NB);
    scanC_kernel<<<NB, 256, 0, stream>>>(offs, partials, N, E);
    posfix_kernel<<<EB, 256, 0, stream>>>(dst, offs, rank, E);
    scatter_ranged_kernel<<<8 * ((E + SCH - 1) / SCH), 256, 0, stream>>>(src, rank, csrsrc, E);

    // --- weight transposes (bf16) ---
    wtrans_kernel<<<3, 256, 0, stream>>>(W1, W2, Wp, WT);
    ushort* WT1 = WT;
    ushort* WT2 = WT + 128 * 128;
    ushort* WTp = WT + 2 * 128 * 128;

    int ggrid = (N + 63) / 64;
    int agrid = (N + 15) / 16;

    // --- layer 1 ---
    mfma_gemm_kernel<true, true, false><<<ggrid, 256, 0, stream>>>(x, WT1, nullptr, featb, N);
    eler_kernel<<<(N * 4 + 255) / 256, 256, 0, stream>>>(featb, al1, ar1, el, er, N * 4);
    aggregate_kernel<false><<<agrid, 256, 0, stream>>>(featb, el, er, b1, offs, csrsrc, h1b, N);

    // --- layer 2 ---
    mfma_gemm_kernel<false, true, false><<<ggrid, 256, 0, stream>>>(h1b, WT2, nullptr, featb, N);
    eler_kernel<<<(N * 4 + 255) / 256, 256, 0, stream>>>(featb, al2, ar2, el, er, N * 4);
    aggregate_kernel<true><<<agrid, 256, 0, stream>>>(featb, el, er, b2, offs, csrsrc, h_out, N);

    // --- projection (reads fp32 h_out, converts to bf16 in-register) ---
    mfma_gemm_kernel<true, false, true><<<ggrid, 256, 0, stream>>>(h_out, WTp, bp, p_out, N);
}